// Round 2
// baseline (479.474 us; speedup 1.0000x reference)
//
#include <hip/hip_runtime.h>
#include <hip/hip_bf16.h>
#include <math.h>

typedef __bf16 bf16;
typedef __bf16 bf16x8 __attribute__((ext_vector_type(8)));
typedef float floatx4 __attribute__((ext_vector_type(4)));

#define T_ 2048
#define D_ 768
#define H_ 12
#define HD_ 64
#define FF_ 3072
#define LOG2E 1.44269504f

typedef __attribute__((address_space(1))) void as1_void;
typedef __attribute__((address_space(3))) void as3_void;

__device__ __forceinline__ floatx4 mfma_bf16(bf16x8 a, bf16x8 b, floatx4 c) {
  return __builtin_amdgcn_mfma_f32_16x16x32_bf16(a, b, c, 0, 0, 0);
}

// async global->LDS, 16B per lane. LDS dest = wave-uniform base + lane*16.
__device__ __forceinline__ void async_ld16(void* lds, const void* g) {
  __builtin_amdgcn_global_load_lds((const as1_void*)g, (as3_void*)lds, 16, 0, 0);
}

// ---------------------------------------------------------------------------
// Convert the 7 fp32 weight matrices to bf16 (contiguous output buffer).
// Segment cumulative bounds (elements):
//   wq 589824 | wk 1179648 | wv 1769472 | wo 2359296 | w1 4718592
//   w2 7077888 | w3 9437184
// ---------------------------------------------------------------------------
__global__ __launch_bounds__(256)
void cvt_k(const float* __restrict__ wq, const float* __restrict__ wk,
           const float* __restrict__ wv, const float* __restrict__ wo,
           const float* __restrict__ w1, const float* __restrict__ w2,
           const float* __restrict__ w3, bf16* __restrict__ o) {
  const long i = ((long)blockIdx.x * 256 + threadIdx.x) * 8;
  const float* s;
  if      (i <  589824) s = wq + i;
  else if (i < 1179648) s = wk + (i -  589824);
  else if (i < 1769472) s = wv + (i - 1179648);
  else if (i < 2359296) s = wo + (i - 1769472);
  else if (i < 4718592) s = w1 + (i - 2359296);
  else if (i < 7077888) s = w2 + (i - 4718592);
  else                  s = w3 + (i - 7077888);
  const floatx4 a = *(const floatx4*)s;
  const floatx4 b = *(const floatx4*)(s + 4);
  bf16x8 r;
#pragma unroll
  for (int j = 0; j < 4; j++) { r[j] = (bf16)a[j]; r[4 + j] = (bf16)b[j]; }
  *(bf16x8*)&o[i] = r;
}

// ---------------------------------------------------------------------------
// GEMM: C[m][n] = sum_k A[m][k] * W[n][k]  (A: MxK bf16, W: NxK bf16)
// 128x128 tile, BK=32, 4 waves (2x2), each wave 64x64 via 4x4 mfma_16x16x32.
// EP=0: bf16 C = acc.  EP=1: f32 C = acc + f32 resid.
// ---------------------------------------------------------------------------
template<int EP>
__device__ __forceinline__ void gemm_core(
    const bf16* __restrict__ A, const bf16* __restrict__ W,
    void* __restrict__ C, const float* __restrict__ resid,
    int N, int K, int m0, int n0)
{
  __shared__ __align__(16) bf16 As[4096];  // 128 rows x 32 cols, contiguous
  __shared__ __align__(16) bf16 Ws[4096];

  const int tid = threadIdx.x;
  const int lane = tid & 63;
  const int wm = tid >> 7;
  const int wn = (tid >> 6) & 1;

  floatx4 acc[4][4] = {};

  const int e0 = tid * 8;
  const int r0 = e0 >> 5;          // 0..63
  const int c0 = e0 & 31;
  const bf16* Ag0 = A + (long)(m0 + r0) * K + c0;
  const bf16* Ag1 = A + (long)(m0 + 64 + r0) * K + c0;
  const bf16* Wg0 = W + (long)(n0 + r0) * K + c0;
  const bf16* Wg1 = W + (long)(n0 + 64 + r0) * K + c0;
  bf16* Al0 = &As[e0];
  bf16* Al1 = &As[2048 + e0];
  bf16* Wl0 = &Ws[e0];
  bf16* Wl1 = &Ws[2048 + e0];

  const int fr = lane & 15;
  const int fk = (lane >> 4) * 8;

  for (int k0 = 0; k0 < K; k0 += 32) {
    __syncthreads();
    async_ld16(Al0, Ag0 + k0);
    async_ld16(Al1, Ag1 + k0);
    async_ld16(Wl0, Wg0 + k0);
    async_ld16(Wl1, Wg1 + k0);
    __syncthreads();
    bf16x8 af[4], bfv[4];
#pragma unroll
    for (int i = 0; i < 4; i++) af[i]  = *(const bf16x8*)&As[(wm * 64 + i * 16 + fr) * 32 + fk];
#pragma unroll
    for (int j = 0; j < 4; j++) bfv[j] = *(const bf16x8*)&Ws[(wn * 64 + j * 16 + fr) * 32 + fk];
#pragma unroll
    for (int i = 0; i < 4; i++)
#pragma unroll
      for (int j = 0; j < 4; j++)
        acc[i][j] = mfma_bf16(af[i], bfv[j], acc[i][j]);
  }

  const int rb = (lane >> 4) * 4;
#pragma unroll
  for (int i = 0; i < 4; i++) {
#pragma unroll
    for (int j = 0; j < 4; j++) {
      const int n = n0 + wn * 64 + j * 16 + fr;
#pragma unroll
      for (int r = 0; r < 4; r++) {
        const int m = m0 + wm * 64 + i * 16 + rb + r;
        const long idx = (long)m * N + n;
        const float v = acc[i][j][r];
        if (EP == 0) ((bf16*)C)[idx]  = (bf16)v;
        else         ((float*)C)[idx] = v + resid[idx];
      }
    }
  }
}

template<int EP>
__global__ __launch_bounds__(256)
void gemm_bt(const bf16* __restrict__ A, const bf16* __restrict__ W,
             void* __restrict__ C, const float* __restrict__ resid, int N, int K) {
  gemm_core<EP>(A, W, C, resid, N, K, blockIdx.y * 128, blockIdx.x * 128);
}

// QKV fused over N=2304: widx = blockIdx.x/6 picks weight/output.
__global__ __launch_bounds__(256)
void gemm_qkv(const bf16* __restrict__ h, const bf16* __restrict__ wq,
              const bf16* __restrict__ wk, const bf16* __restrict__ wv,
              bf16* __restrict__ q, bf16* __restrict__ k, bf16* __restrict__ v) {
  const int widx = blockIdx.x / 6;
  const int nb   = blockIdx.x % 6;
  const bf16* W = (widx == 0) ? wq : (widx == 1) ? wk : wv;
  bf16*       O = (widx == 0) ? q  : (widx == 1) ? k  : v;
  gemm_core<0>(h, W, (void*)O, nullptr, D_, D_, blockIdx.y * 128, nb * 128);
}

// ---------------------------------------------------------------------------
// RMSNorm: out_bf16 = w * x / (sqrt(mean(x^2)) + 1e-6); x, w fp32.
// ---------------------------------------------------------------------------
__global__ __launch_bounds__(256)
void rmsnorm_k(const float* __restrict__ x, const float* __restrict__ wt,
               bf16* __restrict__ o) {
  const int row = blockIdx.x;
  const int tid = threadIdx.x;
  const long off = (long)row * D_;
  float vals[3];
  float ss = 0.f;
#pragma unroll
  for (int i = 0; i < 3; i++) {
    vals[i] = x[off + tid + i * 256];
    ss += vals[i] * vals[i];
  }
#pragma unroll
  for (int d = 1; d < 64; d <<= 1) ss += __shfl_xor(ss, d);
  __shared__ float wsum[4];
  if ((tid & 63) == 0) wsum[tid >> 6] = ss;
  __syncthreads();
  const float tot = wsum[0] + wsum[1] + wsum[2] + wsum[3];
  const float inv = 1.0f / (sqrtf(tot * (1.0f / 768.0f)) + 1e-6f);
#pragma unroll
  for (int i = 0; i < 3; i++)
    o[off + tid + i * 256] = (bf16)(vals[i] * inv * wt[tid + i * 256]);
}

// ---------------------------------------------------------------------------
// RoPE in-place on bf16 q,k; cos/sin fp32 [2048][64] with c[2i]==c[2i+1].
// out[2i] = x[2i]c - x[2i+1]s ; out[2i+1] = x[2i+1]c + x[2i]s
// ---------------------------------------------------------------------------
__global__ __launch_bounds__(256)
void rope_k(bf16* __restrict__ q, bf16* __restrict__ k,
            const float* __restrict__ cosb, const float* __restrict__ sinb) {
  const int idx = blockIdx.x * 256 + threadIdx.x;   // 4096*384 pairs
  const int tkn = idx / 384;
  const int p   = idx % 384;
  const int hh  = p >> 5;
  const int i   = p & 31;
  const int pos = tkn & (T_ - 1);
  const long off = (long)tkn * D_ + hh * HD_ + 2 * i;
  const float c0 = cosb[pos * HD_ + 2 * i];
  const float c1 = cosb[pos * HD_ + 2 * i + 1];
  const float s0 = sinb[pos * HD_ + 2 * i];
  const float s1 = sinb[pos * HD_ + 2 * i + 1];
  const float qe = (float)q[off], qo = (float)q[off + 1];
  q[off]     = (bf16)(qe * c0 - qo * s0);
  q[off + 1] = (bf16)(qo * c1 + qe * s1);
  const float ke = (float)k[off], ko = (float)k[off + 1];
  k[off]     = (bf16)(ke * c0 - ko * s0);
  k[off + 1] = (bf16)(ko * c1 + ke * s1);
}

// ---------------------------------------------------------------------------
// Flash attention, causal. Block = (b,h,q-tile of 128). Wave w owns q rows
// [w*32, w*32+32). KV tiles of 64. Online softmax in registers.
// ---------------------------------------------------------------------------
__global__ __launch_bounds__(256)
void flash_attn(const bf16* __restrict__ q, const bf16* __restrict__ k,
                const bf16* __restrict__ v, bf16* __restrict__ y) {
  const int bh = blockIdx.x >> 4;
  const int qt = blockIdx.x & 15;
  const int b  = bh / H_;
  const int h  = bh % H_;
  const int q0 = qt * 128;

  __shared__ __align__(16) bf16 Qs[128][72];
  __shared__ __align__(16) bf16 Ks[64][72];
  __shared__ __align__(16) bf16 Vt[64][72];    // V transposed: [hd][kv]
  __shared__ __align__(16) bf16 Ps[4][32][72]; // per-wave P, A-operand layout

  const int tid = threadIdx.x, lane = tid & 63, w = tid >> 6;
  const long base = ((long)b * T_) * D_ + h * HD_;

#pragma unroll
  for (int p = 0; p < 4; p++) {      // Q tile 128x64
    const int e = p * 2048 + tid * 8;
    const int r = e >> 6, c = e & 63;
    *(bf16x8*)&Qs[r][c] = *(const bf16x8*)&q[base + (long)(q0 + r) * D_ + c];
  }

  float m_st[2][4], l_st[2][4];
  floatx4 acc_o[2][4] = {};
#pragma unroll
  for (int mt = 0; mt < 2; mt++)
#pragma unroll
    for (int r = 0; r < 4; r++) { m_st[mt][r] = -1e30f; l_st[mt][r] = 0.f; }

  const int fr = lane & 15, fk = (lane >> 4) * 8;
  const int rowb = q0 + w * 32;
  const int nkv = (q0 >> 6) + 2;

  for (int t = 0; t < nkv; t++) {
    const int k0 = t * 64;
    __syncthreads();
#pragma unroll
    for (int p = 0; p < 2; p++) {    // K + V(transposed) tiles 64x64
      const int e = p * 2048 + tid * 8;
      const int r = e >> 6, c = e & 63;
      *(bf16x8*)&Ks[r][c] = *(const bf16x8*)&k[base + (long)(k0 + r) * D_ + c];
      bf16x8 vv = *(const bf16x8*)&v[base + (long)(k0 + r) * D_ + c];
#pragma unroll
      for (int j = 0; j < 8; j++) Vt[c + j][r] = vv[j];
    }
    __syncthreads();

    // S = Q K^T (wave: 32 rows x 64 cols)
    floatx4 s[2][4] = {};
#pragma unroll
    for (int kd = 0; kd < 2; kd++) {
      bf16x8 aq[2], bk[4];
#pragma unroll
      for (int mt = 0; mt < 2; mt++) aq[mt] = *(const bf16x8*)&Qs[w * 32 + mt * 16 + fr][kd * 32 + fk];
#pragma unroll
      for (int nt = 0; nt < 4; nt++) bk[nt] = *(const bf16x8*)&Ks[nt * 16 + fr][kd * 32 + fk];
#pragma unroll
      for (int mt = 0; mt < 2; mt++)
#pragma unroll
        for (int nt = 0; nt < 4; nt++)
          s[mt][nt] = mfma_bf16(aq[mt], bk[nt], s[mt][nt]);
    }

    // scale + causal mask
#pragma unroll
    for (int mt = 0; mt < 2; mt++)
#pragma unroll
      for (int nt = 0; nt < 4; nt++)
#pragma unroll
        for (int r = 0; r < 4; r++) {
          const int row = rowb + mt * 16 + (lane >> 4) * 4 + r;
          const int col = k0 + nt * 16 + fr;
          const float sv = s[mt][nt][r] * 0.125f;
          s[mt][nt][r] = (col > row) ? -1e30f : sv;
        }

    // online softmax update
#pragma unroll
    for (int mt = 0; mt < 2; mt++)
#pragma unroll
      for (int r = 0; r < 4; r++) {
        float mx = fmaxf(fmaxf(s[mt][0][r], s[mt][1][r]), fmaxf(s[mt][2][r], s[mt][3][r]));
        mx = fmaxf(mx, __shfl_xor(mx, 1));
        mx = fmaxf(mx, __shfl_xor(mx, 2));
        mx = fmaxf(mx, __shfl_xor(mx, 4));
        mx = fmaxf(mx, __shfl_xor(mx, 8));
        const float mnew  = fmaxf(m_st[mt][r], mx);
        const float alpha = exp2f((m_st[mt][r] - mnew) * LOG2E);
        m_st[mt][r] = mnew;
        float rs = 0.f;
#pragma unroll
        for (int nt = 0; nt < 4; nt++) {
          const float pv = exp2f((s[mt][nt][r] - mnew) * LOG2E);
          s[mt][nt][r] = pv;
          rs += pv;
        }
        rs += __shfl_xor(rs, 1);
        rs += __shfl_xor(rs, 2);
        rs += __shfl_xor(rs, 4);
        rs += __shfl_xor(rs, 8);
        l_st[mt][r] = l_st[mt][r] * alpha + rs;
#pragma unroll
        for (int ht = 0; ht < 4; ht++) acc_o[mt][ht][r] *= alpha;
      }

    // P: C/D layout -> A-operand layout via LDS
#pragma unroll
    for (int mt = 0; mt < 2; mt++)
#pragma unroll
      for (int nt = 0; nt < 4; nt++)
#pragma unroll
        for (int r = 0; r < 4; r++)
          Ps[w][mt * 16 + (lane >> 4) * 4 + r][nt * 16 + fr] = (bf16)s[mt][nt][r];
    __syncthreads();

    // O += P V
#pragma unroll
    for (int kq = 0; kq < 2; kq++) {
      bf16x8 ap[2], bv[4];
#pragma unroll
      for (int mt = 0; mt < 2; mt++) ap[mt] = *(const bf16x8*)&Ps[w][mt * 16 + fr][kq * 32 + fk];
#pragma unroll
      for (int ht = 0; ht < 4; ht++) bv[ht] = *(const bf16x8*)&Vt[ht * 16 + fr][kq * 32 + fk];
#pragma unroll
      for (int mt = 0; mt < 2; mt++)
#pragma unroll
        for (int ht = 0; ht < 4; ht++)
          acc_o[mt][ht] = mfma_bf16(ap[mt], bv[ht], acc_o[mt][ht]);
    }
  }

#pragma unroll
  for (int mt = 0; mt < 2; mt++)
#pragma unroll
    for (int ht = 0; ht < 4; ht++)
#pragma unroll
      for (int r = 0; r < 4; r++) {
        const int row = q0 + w * 32 + mt * 16 + (lane >> 4) * 4 + r;
        const int hd  = ht * 16 + fr;
        y[base + (long)row * D_ + hd] = (bf16)(acc_o[mt][ht][r] / l_st[mt][r]);
      }
}

// ---------------------------------------------------------------------------
// g1 = silu(g1) * g2, bf16 in-place.
// ---------------------------------------------------------------------------
__global__ __launch_bounds__(256)
void silu_mul_k(bf16* __restrict__ g1, const bf16* __restrict__ g2) {
  const long i0 = ((long)blockIdx.x * 256 + threadIdx.x) * 8;
  bf16x8 a = *(bf16x8*)&g1[i0];
  bf16x8 b = *(const bf16x8*)&g2[i0];
#pragma unroll
  for (int j = 0; j < 8; j++) {
    const float x = (float)a[j];
    const float s = x / (1.f + exp2f(-x * LOG2E));
    a[j] = (bf16)(s * (float)b[j]);
  }
  *(bf16x8*)&g1[i0] = a;
}

// ---------------------------------------------------------------------------
extern "C" void kernel_launch(void* const* d_in, const int* in_sizes, int n_in,
                              void* d_out, int out_size, void* d_ws, size_t ws_size,
                              hipStream_t stream) {
  const float* x    = (const float*)d_in[0];
  const float* wq   = (const float*)d_in[1];
  const float* wk   = (const float*)d_in[2];
  const float* wv   = (const float*)d_in[3];
  const float* wo   = (const float*)d_in[4];
  const float* w1   = (const float*)d_in[5];
  const float* w2   = (const float*)d_in[6];
  const float* w3   = (const float*)d_in[7];
  const float* anw  = (const float*)d_in[8];
  const float* fnw  = (const float*)d_in[9];
  const float* cosb = (const float*)d_in[10];
  const float* sinb = (const float*)d_in[11];

  char* ws = (char*)d_ws;
  // bytes: wb bf16 weights 18,874,368 | q/k/v/y 4x6,291,456 | hn 6,291,456
  //        | xm f32 12,582,912 | g1 25,165,824  => total 88,080,384
  bf16*  wb  = (bf16*)(ws + 0);
  bf16*  wqb = wb;
  bf16*  wkb = wb +  589824;
  bf16*  wvb = wb + 1179648;
  bf16*  wob = wb + 1769472;
  bf16*  w1b = wb + 2359296;
  bf16*  w2b = wb + 4718592;
  bf16*  w3b = wb + 7077888;
  bf16*  qb  = (bf16*)(ws + 18874368);
  bf16*  kb  = (bf16*)(ws + 25165824);
  bf16*  vb  = (bf16*)(ws + 31457280);
  bf16*  yb  = (bf16*)(ws + 37748736);
  bf16*  hn  = (bf16*)(ws + 44040192);
  float* xm  = (float*)(ws + 50331648);
  bf16*  g1  = (bf16*)(ws + 62914560);
  bf16*  g2  = qb;                     // aliases dead q/k/v/y (exactly 25,165,824 B)

  // 0. weights fp32 -> bf16
  cvt_k<<<4608, 256, 0, stream>>>(wq, wk, wv, wo, w1, w2, w3, wb);
  // 1. attn rmsnorm
  rmsnorm_k<<<4096, 256, 0, stream>>>(x, anw, hn);
  // 2. QKV
  gemm_qkv<<<dim3(18, 32), 256, 0, stream>>>(hn, wqb, wkb, wvb, qb, kb, vb);
  // 3. RoPE
  rope_k<<<6144, 256, 0, stream>>>(qb, kb, cosb, sinb);
  // 4. attention
  flash_attn<<<384, 256, 0, stream>>>(qb, kb, vb, yb);
  // 5. wo + residual -> x_mid fp32
  gemm_bt<1><<<dim3(6, 32), 256, 0, stream>>>(yb, wob, (void*)xm, x, 768, 768);
  // 6. ffn rmsnorm
  rmsnorm_k<<<4096, 256, 0, stream>>>(xm, fnw, hn);
  // 7. w1, w2
  gemm_bt<0><<<dim3(24, 32), 256, 0, stream>>>(hn, w1b, (void*)g1, nullptr, 3072, 768);
  gemm_bt<0><<<dim3(24, 32), 256, 0, stream>>>(hn, w2b, (void*)g2, nullptr, 3072, 768);
  // 8. silu(g1)*g2 -> g1
  silu_mul_k<<<6144, 256, 0, stream>>>(g1, g2);
  // 9. w3 + residual -> out fp32
  gemm_bt<1><<<dim3(6, 32), 256, 0, stream>>>(g1, w3b, d_out, xm, 768, 3072);
}

// Round 3
// 380.735 us; speedup vs baseline: 1.2593x; 1.2593x over previous
//
#include <hip/hip_runtime.h>
#include <hip/hip_bf16.h>
#include <math.h>

typedef __bf16 bf16;
typedef __bf16 bf16x4 __attribute__((ext_vector_type(4)));
typedef __bf16 bf16x8 __attribute__((ext_vector_type(8)));
typedef float floatx4 __attribute__((ext_vector_type(4)));

#define T_ 2048
#define D_ 768
#define H_ 12
#define HD_ 64
#define FF_ 3072
#define LOG2E 1.44269504f

typedef __attribute__((address_space(1))) void as1_void;
typedef __attribute__((address_space(3))) void as3_void;

__device__ __forceinline__ floatx4 mfma_bf16(bf16x8 a, bf16x8 b, floatx4 c) {
  return __builtin_amdgcn_mfma_f32_16x16x32_bf16(a, b, c, 0, 0, 0);
}

// async global->LDS, 16B per lane. LDS dest = wave-uniform base + lane*16.
__device__ __forceinline__ void async_ld16(void* lds, const void* g) {
  __builtin_amdgcn_global_load_lds((const as1_void*)g, (as3_void*)lds, 16, 0, 0);
}

// ---------------------------------------------------------------------------
// Convert the 7 fp32 weight matrices to bf16 (contiguous output buffer).
// ---------------------------------------------------------------------------
__global__ __launch_bounds__(256)
void cvt_k(const float* __restrict__ wq, const float* __restrict__ wk,
           const float* __restrict__ wv, const float* __restrict__ wo,
           const float* __restrict__ w1, const float* __restrict__ w2,
           const float* __restrict__ w3, bf16* __restrict__ o) {
  const long i = ((long)blockIdx.x * 256 + threadIdx.x) * 8;
  const float* s;
  if      (i <  589824) s = wq + i;
  else if (i < 1179648) s = wk + (i -  589824);
  else if (i < 1769472) s = wv + (i - 1179648);
  else if (i < 2359296) s = wo + (i - 1769472);
  else if (i < 4718592) s = w1 + (i - 2359296);
  else if (i < 7077888) s = w2 + (i - 4718592);
  else                  s = w3 + (i - 7077888);
  const floatx4 a = *(const floatx4*)s;
  const floatx4 b = *(const floatx4*)(s + 4);
  bf16x8 r;
#pragma unroll
  for (int j = 0; j < 4; j++) { r[j] = (bf16)a[j]; r[4 + j] = (bf16)b[j]; }
  *(bf16x8*)&o[i] = r;
}

// ---------------------------------------------------------------------------
// GEMM 128x128: C[m][n] = sum_k A[m][k] * W[n][k]
// EP=0: bf16 C = acc.  EP=1: f32 C = acc + f32 resid.
// ---------------------------------------------------------------------------
template<int EP>
__device__ __forceinline__ void gemm_core(
    const bf16* __restrict__ A, const bf16* __restrict__ W,
    void* __restrict__ C, const float* __restrict__ resid,
    int N, int K, int m0, int n0)
{
  __shared__ __align__(16) bf16 As[4096];
  __shared__ __align__(16) bf16 Ws[4096];

  const int tid = threadIdx.x;
  const int lane = tid & 63;
  const int wm = tid >> 7;
  const int wn = (tid >> 6) & 1;

  floatx4 acc[4][4] = {};

  const int e0 = tid * 8;
  const int r0 = e0 >> 5;
  const int c0 = e0 & 31;
  const bf16* Ag0 = A + (long)(m0 + r0) * K + c0;
  const bf16* Ag1 = A + (long)(m0 + 64 + r0) * K + c0;
  const bf16* Wg0 = W + (long)(n0 + r0) * K + c0;
  const bf16* Wg1 = W + (long)(n0 + 64 + r0) * K + c0;
  bf16* Al0 = &As[e0];
  bf16* Al1 = &As[2048 + e0];
  bf16* Wl0 = &Ws[e0];
  bf16* Wl1 = &Ws[2048 + e0];

  const int fr = lane & 15;
  const int fk = (lane >> 4) * 8;

  for (int k0 = 0; k0 < K; k0 += 32) {
    __syncthreads();
    async_ld16(Al0, Ag0 + k0);
    async_ld16(Al1, Ag1 + k0);
    async_ld16(Wl0, Wg0 + k0);
    async_ld16(Wl1, Wg1 + k0);
    __syncthreads();
    bf16x8 af[4], bfv[4];
#pragma unroll
    for (int i = 0; i < 4; i++) af[i]  = *(const bf16x8*)&As[(wm * 64 + i * 16 + fr) * 32 + fk];
#pragma unroll
    for (int j = 0; j < 4; j++) bfv[j] = *(const bf16x8*)&Ws[(wn * 64 + j * 16 + fr) * 32 + fk];
#pragma unroll
    for (int i = 0; i < 4; i++)
#pragma unroll
      for (int j = 0; j < 4; j++)
        acc[i][j] = mfma_bf16(af[i], bfv[j], acc[i][j]);
  }

  const int rb = (lane >> 4) * 4;
#pragma unroll
  for (int i = 0; i < 4; i++) {
#pragma unroll
    for (int j = 0; j < 4; j++) {
      const int n = n0 + wn * 64 + j * 16 + fr;
#pragma unroll
      for (int r = 0; r < 4; r++) {
        const int m = m0 + wm * 64 + i * 16 + rb + r;
        const long idx = (long)m * N + n;
        const float v = acc[i][j][r];
        if (EP == 0) ((bf16*)C)[idx]  = (bf16)v;
        else         ((float*)C)[idx] = v + resid[idx];
      }
    }
  }
}

template<int EP>
__global__ __launch_bounds__(256)
void gemm_bt(const bf16* __restrict__ A, const bf16* __restrict__ W,
             void* __restrict__ C, const float* __restrict__ resid, int N, int K) {
  gemm_core<EP>(A, W, C, resid, N, K, blockIdx.y * 128, blockIdx.x * 128);
}

// QKV fused over N=2304: widx = blockIdx.x/6 picks weight/output.
__global__ __launch_bounds__(256)
void gemm_qkv(const bf16* __restrict__ h, const bf16* __restrict__ wq,
              const bf16* __restrict__ wk, const bf16* __restrict__ wv,
              bf16* __restrict__ q, bf16* __restrict__ k, bf16* __restrict__ v) {
  const int widx = blockIdx.x / 6;
  const int nb   = blockIdx.x % 6;
  const bf16* W = (widx == 0) ? wq : (widx == 1) ? wk : wv;
  bf16*       O = (widx == 0) ? q  : (widx == 1) ? k  : v;
  gemm_core<0>(h, W, (void*)O, nullptr, D_, D_, blockIdx.y * 128, nb * 128);
}

// ---------------------------------------------------------------------------
// GEMM 128x64 tile (for N=768 outputs: 12 x-blocks x 32 y-blocks = 384 blocks)
// wave (wm,wn): m = wm*64.., n = wn*32..  acc[4][2]
// ---------------------------------------------------------------------------
template<int EP>
__global__ __launch_bounds__(256)
void gemm_bt_n64(const bf16* __restrict__ A, const bf16* __restrict__ W,
                 void* __restrict__ C, const float* __restrict__ resid,
                 int N, int K) {
  __shared__ __align__(16) bf16 As[4096];   // 128 x 32
  __shared__ __align__(16) bf16 Ws[2048];   // 64 x 32

  const int m0 = blockIdx.y * 128, n0 = blockIdx.x * 64;
  const int tid = threadIdx.x;
  const int lane = tid & 63;
  const int wm = tid >> 7;
  const int wn = (tid >> 6) & 1;

  floatx4 acc[4][2] = {};

  const int e0 = tid * 8;
  const int r0 = e0 >> 5;
  const int c0 = e0 & 31;
  const bf16* Ag0 = A + (long)(m0 + r0) * K + c0;
  const bf16* Ag1 = A + (long)(m0 + 64 + r0) * K + c0;
  const bf16* Wg0 = W + (long)(n0 + r0) * K + c0;
  bf16* Al0 = &As[e0];
  bf16* Al1 = &As[2048 + e0];
  bf16* Wl0 = &Ws[e0];     // e0 < 2048 for tid < 256 ✓

  const int fr = lane & 15;
  const int fk = (lane >> 4) * 8;

  for (int k0 = 0; k0 < K; k0 += 32) {
    __syncthreads();
    async_ld16(Al0, Ag0 + k0);
    async_ld16(Al1, Ag1 + k0);
    async_ld16(Wl0, Wg0 + k0);
    __syncthreads();
    bf16x8 af[4], bfv[2];
#pragma unroll
    for (int i = 0; i < 4; i++) af[i]  = *(const bf16x8*)&As[(wm * 64 + i * 16 + fr) * 32 + fk];
#pragma unroll
    for (int j = 0; j < 2; j++) bfv[j] = *(const bf16x8*)&Ws[(wn * 32 + j * 16 + fr) * 32 + fk];
#pragma unroll
    for (int i = 0; i < 4; i++)
#pragma unroll
      for (int j = 0; j < 2; j++)
        acc[i][j] = mfma_bf16(af[i], bfv[j], acc[i][j]);
  }

  const int rb = (lane >> 4) * 4;
#pragma unroll
  for (int i = 0; i < 4; i++) {
#pragma unroll
    for (int j = 0; j < 2; j++) {
      const int n = n0 + wn * 32 + j * 16 + fr;
#pragma unroll
      for (int r = 0; r < 4; r++) {
        const int m = m0 + wm * 64 + i * 16 + rb + r;
        const long idx = (long)m * N + n;
        const float v = acc[i][j][r];
        if (EP == 0) ((bf16*)C)[idx]  = (bf16)v;
        else         ((float*)C)[idx] = v + resid[idx];
      }
    }
  }
}

// ---------------------------------------------------------------------------
// RMSNorm: out_bf16 = w * x / (sqrt(mean(x^2)) + 1e-6); x, w fp32.
// ---------------------------------------------------------------------------
__global__ __launch_bounds__(256)
void rmsnorm_k(const float* __restrict__ x, const float* __restrict__ wt,
               bf16* __restrict__ o) {
  const int row = blockIdx.x;
  const int tid = threadIdx.x;
  const long off = (long)row * D_;
  float vals[3];
  float ss = 0.f;
#pragma unroll
  for (int i = 0; i < 3; i++) {
    vals[i] = x[off + tid + i * 256];
    ss += vals[i] * vals[i];
  }
#pragma unroll
  for (int d = 1; d < 64; d <<= 1) ss += __shfl_xor(ss, d);
  __shared__ float wsum[4];
  if ((tid & 63) == 0) wsum[tid >> 6] = ss;
  __syncthreads();
  const float tot = wsum[0] + wsum[1] + wsum[2] + wsum[3];
  const float inv = 1.0f / (sqrtf(tot * (1.0f / 768.0f)) + 1e-6f);
#pragma unroll
  for (int i = 0; i < 3; i++)
    o[off + tid + i * 256] = (bf16)(vals[i] * inv * wt[tid + i * 256]);
}

// ---------------------------------------------------------------------------
// RoPE in-place on bf16 q,k; cos/sin fp32 [2048][64] with c[2i]==c[2i+1].
// ---------------------------------------------------------------------------
__global__ __launch_bounds__(256)
void rope_k(bf16* __restrict__ q, bf16* __restrict__ k,
            const float* __restrict__ cosb, const float* __restrict__ sinb) {
  const int idx = blockIdx.x * 256 + threadIdx.x;
  const int tkn = idx / 384;
  const int p   = idx % 384;
  const int hh  = p >> 5;
  const int i   = p & 31;
  const int pos = tkn & (T_ - 1);
  const long off = (long)tkn * D_ + hh * HD_ + 2 * i;
  const float c0 = cosb[pos * HD_ + 2 * i];
  const float c1 = cosb[pos * HD_ + 2 * i + 1];
  const float s0 = sinb[pos * HD_ + 2 * i];
  const float s1 = sinb[pos * HD_ + 2 * i + 1];
  const float qe = (float)q[off], qo = (float)q[off + 1];
  q[off]     = (bf16)(qe * c0 - qo * s0);
  q[off + 1] = (bf16)(qo * c1 + qe * s1);
  const float ke = (float)k[off], ko = (float)k[off + 1];
  k[off]     = (bf16)(ke * c0 - ko * s0);
  k[off + 1] = (bf16)(ko * c1 + ke * s1);
}

// ---------------------------------------------------------------------------
// V transpose: v [b][t][h][hd] -> vt [b*H+h][hd][t]  (per-head 64 x 2048)
// Block = (bh, t-tile of 64). LDS tile [t][hd], write [hd][t].
// ---------------------------------------------------------------------------
__global__ __launch_bounds__(256)
void vtrans_k(const bf16* __restrict__ v, bf16* __restrict__ vt) {
  const int bh = blockIdx.x >> 5;
  const int tt = blockIdx.x & 31;
  const int b = bh / H_, h = bh % H_;
  __shared__ __align__(16) bf16 Vs[64][72];
  const int tid = threadIdx.x;
  const int row = tid >> 2;            // local t
  const int c0  = (tid & 3) * 16;      // hd col (2 chunks of 8)
  const long gin = ((long)(b * T_ + tt * 64 + row)) * D_ + h * HD_ + c0;
  *(bf16x8*)&Vs[row][c0]     = *(const bf16x8*)&v[gin];
  *(bf16x8*)&Vs[row][c0 + 8] = *(const bf16x8*)&v[gin + 8];
  __syncthreads();
  const int hd = tid >> 2;             // out row
  const int t0 = (tid & 3) * 16;       // out t chunk
  bf16x8 o0, o1;
#pragma unroll
  for (int j = 0; j < 8; j++) { o0[j] = Vs[t0 + j][hd]; o1[j] = Vs[t0 + 8 + j][hd]; }
  const long gout = ((long)(bh * HD_ + hd)) * T_ + tt * 64 + t0;
  *(bf16x8*)&vt[gout]     = o0;
  *(bf16x8*)&vt[gout + 8] = o1;
}

// ---------------------------------------------------------------------------
// Flash attention v2, causal. Block = (bh, q-tile of 64). 4 waves; wave w owns
// q rows [w*16, w*16+16). KV tiles of 64. S^T = K Q^T (softmax state lives in
// col=lane&15 = q domain -> 2 shfls per reduction); O^T = V^T P^T (same domain,
// no cross-lane alpha moves). P packed as b64 vector LDS writes, per-wave Ps.
// ---------------------------------------------------------------------------
__global__ __launch_bounds__(256, 4)
void flash_attn(const bf16* __restrict__ q, const bf16* __restrict__ k,
                const bf16* __restrict__ vtg, bf16* __restrict__ y) {
  const int bh = blockIdx.x >> 5;
  const int qt = blockIdx.x & 31;
  const int b  = bh / H_;
  const int h  = bh % H_;
  const int q0 = qt * 64;

  __shared__ __align__(16) bf16 Qs[64][72];
  __shared__ __align__(16) bf16 Ks[64][72];
  __shared__ __align__(16) bf16 Vt[64][72];      // [hd][kv]
  __shared__ __align__(16) bf16 Ps[4][16][72];   // per-wave, [q][kv]

  const int tid = threadIdx.x, lane = tid & 63, w = tid >> 6;
  const int fr = lane & 15, quad = lane >> 4, fk = quad * 8;
  const long base = ((long)b * T_) * D_ + h * HD_;
  const long vbase = (long)bh * HD_ * T_;

  // stage Q (64 x 64)
  {
    const int srow = tid >> 2, scol = (tid & 3) * 16;
    const long g = base + (long)(q0 + srow) * D_ + scol;
    *(bf16x8*)&Qs[srow][scol]     = *(const bf16x8*)&q[g];
    *(bf16x8*)&Qs[srow][scol + 8] = *(const bf16x8*)&q[g + 8];
  }

  float m_st = -1e30f, l_st = 0.f;
  floatx4 o[4] = {};
  const float SC = 0.125f * LOG2E;   // scores tracked in log2 domain

  for (int t = 0; t <= qt; t++) {
    const int k0 = t * 64;
    __syncthreads();
    {
      const int srow = tid >> 2, scol = (tid & 3) * 16;
      const long kg = base + (long)(k0 + srow) * D_ + scol;
      *(bf16x8*)&Ks[srow][scol]     = *(const bf16x8*)&k[kg];
      *(bf16x8*)&Ks[srow][scol + 8] = *(const bf16x8*)&k[kg + 8];
      const long vg = vbase + (long)srow * T_ + k0 + scol;
      *(bf16x8*)&Vt[srow][scol]     = *(const bf16x8*)&vtg[vg];
      *(bf16x8*)&Vt[srow][scol + 8] = *(const bf16x8*)&vtg[vg + 8];
    }
    __syncthreads();

    // S^T[kv][q]: A = K rows [kv][d], B = Q rows [q][d]
    floatx4 s[4] = {};
#pragma unroll
    for (int kd = 0; kd < 2; kd++) {
      const bf16x8 bq = *(const bf16x8*)&Qs[w * 16 + fr][kd * 32 + fk];
#pragma unroll
      for (int kt = 0; kt < 4; kt++) {
        const bf16x8 ak = *(const bf16x8*)&Ks[kt * 16 + fr][kd * 32 + fk];
        s[kt] = mfma_bf16(ak, bq, s[kt]);
      }
    }

    // scale to log2 domain + causal mask (last tile only; uniform branch)
    if (t == qt) {
      const int qloc = w * 16 + fr;
#pragma unroll
      for (int kt = 0; kt < 4; kt++)
#pragma unroll
        for (int r = 0; r < 4; r++) {
          const int kvloc = kt * 16 + quad * 4 + r;
          s[kt][r] = (kvloc > qloc) ? -1e30f : s[kt][r] * SC;
        }
    } else {
#pragma unroll
      for (int kt = 0; kt < 4; kt++)
#pragma unroll
        for (int r = 0; r < 4; r++) s[kt][r] *= SC;
    }

    // online softmax for row q = w*16+fr (16 in-lane values + 2 shfls)
    float mx = -1e30f;
#pragma unroll
    for (int kt = 0; kt < 4; kt++)
#pragma unroll
      for (int r = 0; r < 4; r++) mx = fmaxf(mx, s[kt][r]);
    mx = fmaxf(mx, __shfl_xor(mx, 16));
    mx = fmaxf(mx, __shfl_xor(mx, 32));
    const float mnew  = fmaxf(m_st, mx);
    const float alpha = exp2f(m_st - mnew);
    m_st = mnew;
    float rs = 0.f;
#pragma unroll
    for (int kt = 0; kt < 4; kt++)
#pragma unroll
      for (int r = 0; r < 4; r++) {
        const float pv = exp2f(s[kt][r] - mnew);
        s[kt][r] = pv;
        rs += pv;
      }
    rs += __shfl_xor(rs, 16);
    rs += __shfl_xor(rs, 32);
    l_st = l_st * alpha + rs;
#pragma unroll
    for (int ht = 0; ht < 4; ht++) o[ht] *= alpha;

    // pack P (4 consecutive kv per lane) -> Ps[w][q][kv], vector b64 writes
#pragma unroll
    for (int kt = 0; kt < 4; kt++) {
      bf16x4 pk;
#pragma unroll
      for (int r = 0; r < 4; r++) pk[r] = (bf16)s[kt][r];
      *(bf16x4*)&Ps[w][fr][kt * 16 + quad * 4] = pk;
    }
    // per-wave Ps: same-wave write->read, compiler's lgkmcnt handles ordering

    // O^T[hd][q] += : A = Vt rows [hd][kv], B = Ps rows [q][kv]
#pragma unroll
    for (int kq = 0; kq < 2; kq++) {
      const bf16x8 bp = *(const bf16x8*)&Ps[w][fr][kq * 32 + fk];
#pragma unroll
      for (int ht = 0; ht < 4; ht++) {
        const bf16x8 av = *(const bf16x8*)&Vt[ht * 16 + fr][kq * 32 + fk];
        o[ht] = mfma_bf16(av, bp, o[ht]);
      }
    }
  }

  // epilogue: lane holds O^T[hd=ht*16+quad*4+r][q=w*16+fr]; divide by l, store
  const float inv = 1.0f / l_st;
  const long yrow = base + (long)(q0 + w * 16 + fr) * D_;
#pragma unroll
  for (int ht = 0; ht < 4; ht++) {
    bf16x4 pk;
#pragma unroll
    for (int r = 0; r < 4; r++) pk[r] = (bf16)(o[ht][r] * inv);
    *(bf16x4*)&y[yrow + ht * 16 + quad * 4] = pk;
  }
}

// ---------------------------------------------------------------------------
// g1 = silu(g1) * g2, bf16 in-place.
// ---------------------------------------------------------------------------
__global__ __launch_bounds__(256)
void silu_mul_k(bf16* __restrict__ g1, const bf16* __restrict__ g2) {
  const long i0 = ((long)blockIdx.x * 256 + threadIdx.x) * 8;
  bf16x8 a = *(bf16x8*)&g1[i0];
  bf16x8 b = *(const bf16x8*)&g2[i0];
#pragma unroll
  for (int j = 0; j < 8; j++) {
    const float x = (float)a[j];
    const float s = x / (1.f + exp2f(-x * LOG2E));
    a[j] = (bf16)(s * (float)b[j]);
  }
  *(bf16x8*)&g1[i0] = a;
}

// ---------------------------------------------------------------------------
extern "C" void kernel_launch(void* const* d_in, const int* in_sizes, int n_in,
                              void* d_out, int out_size, void* d_ws, size_t ws_size,
                              hipStream_t stream) {
  const float* x    = (const float*)d_in[0];
  const float* wq   = (const float*)d_in[1];
  const float* wk   = (const float*)d_in[2];
  const float* wv   = (const float*)d_in[3];
  const float* wo   = (const float*)d_in[4];
  const float* w1   = (const float*)d_in[5];
  const float* w2   = (const float*)d_in[6];
  const float* w3   = (const float*)d_in[7];
  const float* anw  = (const float*)d_in[8];
  const float* fnw  = (const float*)d_in[9];
  const float* cosb = (const float*)d_in[10];
  const float* sinb = (const float*)d_in[11];

  char* ws = (char*)d_ws;
  // bytes: wb 18,874,368 | q/k/v/y 4x6,291,456 | hn 6,291,456 | xm f32
  // 12,582,912 | g1 25,165,824 => total 88,080,384.
  // vt aliases g1's start (used only during flash; g1 written later).
  // g2 aliases dead q/k/v/y region.
  bf16*  wb  = (bf16*)(ws + 0);
  bf16*  wqb = wb;
  bf16*  wkb = wb +  589824;
  bf16*  wvb = wb + 1179648;
  bf16*  wob = wb + 1769472;
  bf16*  w1b = wb + 2359296;
  bf16*  w2b = wb + 4718592;
  bf16*  w3b = wb + 7077888;
  bf16*  qb  = (bf16*)(ws + 18874368);
  bf16*  kb  = (bf16*)(ws + 25165824);
  bf16*  vb  = (bf16*)(ws + 31457280);
  bf16*  yb  = (bf16*)(ws + 37748736);
  bf16*  hn  = (bf16*)(ws + 44040192);
  float* xm  = (float*)(ws + 50331648);
  bf16*  g1  = (bf16*)(ws + 62914560);
  bf16*  vt  = (bf16*)(ws + 62914560);  // 6,291,456 B, dead before g1 is written
  bf16*  g2  = qb;

  // 0. weights fp32 -> bf16
  cvt_k<<<4608, 256, 0, stream>>>(wq, wk, wv, wo, w1, w2, w3, wb);
  // 1. attn rmsnorm
  rmsnorm_k<<<4096, 256, 0, stream>>>(x, anw, hn);
  // 2. QKV
  gemm_qkv<<<dim3(18, 32), 256, 0, stream>>>(hn, wqb, wkb, wvb, qb, kb, vb);
  // 3. RoPE
  rope_k<<<6144, 256, 0, stream>>>(qb, kb, cosb, sinb);
  // 3b. V transpose -> [bh][hd][t]
  vtrans_k<<<768, 256, 0, stream>>>(vb, vt);
  // 4. attention
  flash_attn<<<768, 256, 0, stream>>>(qb, kb, vt, yb);
  // 5. wo + residual -> x_mid fp32
  gemm_bt_n64<1><<<dim3(12, 32), 256, 0, stream>>>(yb, wob, (void*)xm, x, 768, 768);
  // 6. ffn rmsnorm
  rmsnorm_k<<<4096, 256, 0, stream>>>(xm, fnw, hn);
  // 7. w1, w2
  gemm_bt<0><<<dim3(24, 32), 256, 0, stream>>>(hn, w1b, (void*)g1, nullptr, 3072, 768);
  gemm_bt<0><<<dim3(24, 32), 256, 0, stream>>>(hn, w2b, (void*)g2, nullptr, 3072, 768);
  // 8. silu(g1)*g2 -> g1
  silu_mul_k<<<6144, 256, 0, stream>>>(g1, g2);
  // 9. w3 + residual -> out fp32
  gemm_bt_n64<1><<<dim3(12, 32), 256, 0, stream>>>(g1, w3b, d_out, xm, 768, 3072);
}

// Round 4
// 347.456 us; speedup vs baseline: 1.3800x; 1.0958x over previous
//
#include <hip/hip_runtime.h>
#include <hip/hip_bf16.h>
#include <math.h>

typedef __bf16 bf16;
typedef __bf16 bf16x4 __attribute__((ext_vector_type(4)));
typedef __bf16 bf16x8 __attribute__((ext_vector_type(8)));
typedef float floatx4 __attribute__((ext_vector_type(4)));

#define T_ 2048
#define D_ 768
#define H_ 12
#define HD_ 64
#define FF_ 3072
#define LOG2E 1.44269504f
#define LDP 72   // padded LDS row stride (elems): 144 B = 36 banks -> conflict-free

__device__ __forceinline__ floatx4 mfma_bf16(bf16x8 a, bf16x8 b, floatx4 c) {
  return __builtin_amdgcn_mfma_f32_16x16x32_bf16(a, b, c, 0, 0, 0);
}

// ---------------------------------------------------------------------------
// Convert the 7 fp32 weight matrices to bf16 (contiguous output buffer).
// ---------------------------------------------------------------------------
__global__ __launch_bounds__(256)
void cvt_k(const float* __restrict__ wq, const float* __restrict__ wk,
           const float* __restrict__ wv, const float* __restrict__ wo,
           const float* __restrict__ w1, const float* __restrict__ w2,
           const float* __restrict__ w3, bf16* __restrict__ o) {
  const long i = ((long)blockIdx.x * 256 + threadIdx.x) * 8;
  const float* s;
  if      (i <  589824) s = wq + i;
  else if (i < 1179648) s = wk + (i -  589824);
  else if (i < 1769472) s = wv + (i - 1179648);
  else if (i < 2359296) s = wo + (i - 1769472);
  else if (i < 4718592) s = w1 + (i - 2359296);
  else if (i < 7077888) s = w2 + (i - 4718592);
  else                  s = w3 + (i - 7077888);
  const floatx4 a = *(const floatx4*)s;
  const floatx4 b = *(const floatx4*)(s + 4);
  bf16x8 r;
#pragma unroll
  for (int j = 0; j < 4; j++) { r[j] = (bf16)a[j]; r[4 + j] = (bf16)b[j]; }
  *(bf16x8*)&o[i] = r;
}

// ---------------------------------------------------------------------------
// GEMM 128x128 tile, BK=64, register-prefetch pipeline.
// C[m][n] = sum_k A[m][k] * W[n][k].  EP=0: bf16 C.  EP=1: f32 C = acc+resid.
// ---------------------------------------------------------------------------
template<int EP>
__device__ __forceinline__ void gemm128_core(
    const bf16* __restrict__ A, const bf16* __restrict__ W,
    void* __restrict__ C, const float* __restrict__ resid,
    int N, int K, int m0, int n0)
{
  __shared__ __align__(16) bf16 As[128 * LDP];
  __shared__ __align__(16) bf16 Ws[128 * LDP];

  const int tid = threadIdx.x;
  const int lane = tid & 63;
  const int wm = tid >> 7;
  const int wn = (tid >> 6) & 1;
  const int fr = lane & 15;
  const int fk = (lane >> 4) * 8;

  floatx4 acc[4][4] = {};

  // staging: thread t writes rows (t/8 + c*32), cols (t%8)*8 .. +7
  const int ar = tid >> 3;
  const int ac = (tid & 7) * 8;
  const bf16* Aptr = A + (long)(m0 + ar) * K + ac;
  const bf16* Wptr = W + (long)(n0 + ar) * K + ac;
  const long rstep = (long)32 * K;

  bf16x8 apf[4], wpf[4];
#pragma unroll
  for (int c = 0; c < 4; c++) apf[c] = *(const bf16x8*)(Aptr + c * rstep);
#pragma unroll
  for (int c = 0; c < 4; c++) wpf[c] = *(const bf16x8*)(Wptr + c * rstep);

  const int ns = K >> 6;
  for (int ks = 0; ks < ns; ks++) {
    __syncthreads();                       // prev-step LDS consumers done
#pragma unroll
    for (int c = 0; c < 4; c++) *(bf16x8*)&As[(ar + c * 32) * LDP + ac] = apf[c];
#pragma unroll
    for (int c = 0; c < 4; c++) *(bf16x8*)&Ws[(ar + c * 32) * LDP + ac] = wpf[c];
    __syncthreads();
    // prefetch next tile (clamped re-load of last tile on final iter)
    const long koff = (long)((ks + 1 < ns) ? ks + 1 : ks) * 64;
#pragma unroll
    for (int c = 0; c < 4; c++) apf[c] = *(const bf16x8*)(Aptr + koff + c * rstep);
#pragma unroll
    for (int c = 0; c < 4; c++) wpf[c] = *(const bf16x8*)(Wptr + koff + c * rstep);
#pragma unroll
    for (int kc = 0; kc < 2; kc++) {
      bf16x8 af[4], bfv[4];
#pragma unroll
      for (int i = 0; i < 4; i++) af[i]  = *(const bf16x8*)&As[(wm * 64 + i * 16 + fr) * LDP + kc * 32 + fk];
#pragma unroll
      for (int j = 0; j < 4; j++) bfv[j] = *(const bf16x8*)&Ws[(wn * 64 + j * 16 + fr) * LDP + kc * 32 + fk];
#pragma unroll
      for (int i = 0; i < 4; i++)
#pragma unroll
        for (int j = 0; j < 4; j++)
          acc[i][j] = mfma_bf16(af[i], bfv[j], acc[i][j]);
    }
  }

  const int rb = (lane >> 4) * 4;
#pragma unroll
  for (int i = 0; i < 4; i++) {
#pragma unroll
    for (int j = 0; j < 4; j++) {
      const int n = n0 + wn * 64 + j * 16 + fr;
#pragma unroll
      for (int r = 0; r < 4; r++) {
        const int m = m0 + wm * 64 + i * 16 + rb + r;
        const long idx = (long)m * N + n;
        const float v = acc[i][j][r];
        if (EP == 0) ((bf16*)C)[idx]  = (bf16)v;
        else         ((float*)C)[idx] = v + resid[idx];
      }
    }
  }
}

template<int EP>
__global__ __launch_bounds__(256)
void gemm_bt(const bf16* __restrict__ A, const bf16* __restrict__ W,
             void* __restrict__ C, const float* __restrict__ resid, int N, int K) {
  gemm128_core<EP>(A, W, C, resid, N, K, blockIdx.y * 128, blockIdx.x * 128);
}

// QKV fused over N=2304: widx = blockIdx.x/6 picks weight/output.
__global__ __launch_bounds__(256)
void gemm_qkv(const bf16* __restrict__ h, const bf16* __restrict__ wq,
              const bf16* __restrict__ wk, const bf16* __restrict__ wv,
              bf16* __restrict__ q, bf16* __restrict__ k, bf16* __restrict__ v) {
  const int widx = blockIdx.x / 6;
  const int nb   = blockIdx.x % 6;
  const bf16* W = (widx == 0) ? wq : (widx == 1) ? wk : wv;
  bf16*       O = (widx == 0) ? q  : (widx == 1) ? k  : v;
  gemm128_core<0>(h, W, (void*)O, nullptr, D_, D_, blockIdx.y * 128, nb * 128);
}

// ---------------------------------------------------------------------------
// GEMM 128x64 tile for N=768 outputs (wo, w3). Grid = 384 1-D, XCD-swizzled:
// XCD x (= L&7) handles m-stripes [4x,4x+4) x all 12 n -> per-XCD working set
// (4 A-stripes + W band) tracks L2. BK=64, register-prefetch pipeline.
// ---------------------------------------------------------------------------
template<int EP>
__global__ __launch_bounds__(256)
void gemm_n64(const bf16* __restrict__ A, const bf16* __restrict__ W,
              void* __restrict__ C, const float* __restrict__ resid,
              int N, int K) {
  __shared__ __align__(16) bf16 As[128 * LDP];
  __shared__ __align__(16) bf16 Ws[64 * LDP];

  const int L  = blockIdx.x;
  const int j  = L >> 3;
  const int mb = (L & 7) * 4 + (j / 12);
  const int nb = j % 12;
  const int m0 = mb * 128, n0 = nb * 64;

  const int tid = threadIdx.x;
  const int lane = tid & 63;
  const int wm = tid >> 7;
  const int wn = (tid >> 6) & 1;
  const int fr = lane & 15;
  const int fk = (lane >> 4) * 8;

  floatx4 acc[4][2] = {};

  const int ar = tid >> 3;
  const int ac = (tid & 7) * 8;
  const bf16* Aptr = A + (long)(m0 + ar) * K + ac;
  const bf16* Wptr = W + (long)(n0 + ar) * K + ac;
  const long rstep = (long)32 * K;

  bf16x8 apf[4], wpf[2];
#pragma unroll
  for (int c = 0; c < 4; c++) apf[c] = *(const bf16x8*)(Aptr + c * rstep);
#pragma unroll
  for (int c = 0; c < 2; c++) wpf[c] = *(const bf16x8*)(Wptr + c * rstep);

  const int ns = K >> 6;
  for (int ks = 0; ks < ns; ks++) {
    __syncthreads();
#pragma unroll
    for (int c = 0; c < 4; c++) *(bf16x8*)&As[(ar + c * 32) * LDP + ac] = apf[c];
#pragma unroll
    for (int c = 0; c < 2; c++) *(bf16x8*)&Ws[(ar + c * 32) * LDP + ac] = wpf[c];
    __syncthreads();
    const long koff = (long)((ks + 1 < ns) ? ks + 1 : ks) * 64;
#pragma unroll
    for (int c = 0; c < 4; c++) apf[c] = *(const bf16x8*)(Aptr + koff + c * rstep);
#pragma unroll
    for (int c = 0; c < 2; c++) wpf[c] = *(const bf16x8*)(Wptr + koff + c * rstep);
#pragma unroll
    for (int kc = 0; kc < 2; kc++) {
      bf16x8 af[4], bfv[2];
#pragma unroll
      for (int i = 0; i < 4; i++) af[i]  = *(const bf16x8*)&As[(wm * 64 + i * 16 + fr) * LDP + kc * 32 + fk];
#pragma unroll
      for (int j2 = 0; j2 < 2; j2++) bfv[j2] = *(const bf16x8*)&Ws[(wn * 32 + j2 * 16 + fr) * LDP + kc * 32 + fk];
#pragma unroll
      for (int i = 0; i < 4; i++)
#pragma unroll
        for (int j2 = 0; j2 < 2; j2++)
          acc[i][j2] = mfma_bf16(af[i], bfv[j2], acc[i][j2]);
    }
  }

  const int rb = (lane >> 4) * 4;
#pragma unroll
  for (int i = 0; i < 4; i++) {
#pragma unroll
    for (int j2 = 0; j2 < 2; j2++) {
      const int n = n0 + wn * 32 + j2 * 16 + fr;
#pragma unroll
      for (int r = 0; r < 4; r++) {
        const int m = m0 + wm * 64 + i * 16 + rb + r;
        const long idx = (long)m * N + n;
        const float v = acc[i][j2][r];
        if (EP == 0) ((bf16*)C)[idx]  = (bf16)v;
        else         ((float*)C)[idx] = v + resid[idx];
      }
    }
  }
}

// ---------------------------------------------------------------------------
// RMSNorm: out_bf16 = w * x / (sqrt(mean(x^2)) + 1e-6); x, w fp32.
// ---------------------------------------------------------------------------
__global__ __launch_bounds__(256)
void rmsnorm_k(const float* __restrict__ x, const float* __restrict__ wt,
               bf16* __restrict__ o) {
  const int row = blockIdx.x;
  const int tid = threadIdx.x;
  const long off = (long)row * D_;
  float vals[3];
  float ss = 0.f;
#pragma unroll
  for (int i = 0; i < 3; i++) {
    vals[i] = x[off + tid + i * 256];
    ss += vals[i] * vals[i];
  }
#pragma unroll
  for (int d = 1; d < 64; d <<= 1) ss += __shfl_xor(ss, d);
  __shared__ float wsum[4];
  if ((tid & 63) == 0) wsum[tid >> 6] = ss;
  __syncthreads();
  const float tot = wsum[0] + wsum[1] + wsum[2] + wsum[3];
  const float inv = 1.0f / (sqrtf(tot * (1.0f / 768.0f)) + 1e-6f);
#pragma unroll
  for (int i = 0; i < 3; i++)
    o[off + tid + i * 256] = (bf16)(vals[i] * inv * wt[tid + i * 256]);
}

// ---------------------------------------------------------------------------
// RoPE in-place on bf16 q,k; cos/sin fp32 [2048][64] with c[2i]==c[2i+1].
// ---------------------------------------------------------------------------
__global__ __launch_bounds__(256)
void rope_k(bf16* __restrict__ q, bf16* __restrict__ k,
            const float* __restrict__ cosb, const float* __restrict__ sinb) {
  const int idx = blockIdx.x * 256 + threadIdx.x;
  const int tkn = idx / 384;
  const int p   = idx % 384;
  const int hh  = p >> 5;
  const int i   = p & 31;
  const int pos = tkn & (T_ - 1);
  const long off = (long)tkn * D_ + hh * HD_ + 2 * i;
  const float c0 = cosb[pos * HD_ + 2 * i];
  const float c1 = cosb[pos * HD_ + 2 * i + 1];
  const float s0 = sinb[pos * HD_ + 2 * i];
  const float s1 = sinb[pos * HD_ + 2 * i + 1];
  const float qe = (float)q[off], qo = (float)q[off + 1];
  q[off]     = (bf16)(qe * c0 - qo * s0);
  q[off + 1] = (bf16)(qo * c1 + qe * s1);
  const float ke = (float)k[off], ko = (float)k[off + 1];
  k[off]     = (bf16)(ke * c0 - ko * s0);
  k[off + 1] = (bf16)(ko * c1 + ke * s1);
}

// ---------------------------------------------------------------------------
// V transpose: v [b][t][h][hd] -> vt [b*H+h][hd][t]  (per-head 64 x 2048)
// ---------------------------------------------------------------------------
__global__ __launch_bounds__(256)
void vtrans_k(const bf16* __restrict__ v, bf16* __restrict__ vt) {
  const int bh = blockIdx.x >> 5;
  const int tt = blockIdx.x & 31;
  const int b = bh / H_, h = bh % H_;
  __shared__ __align__(16) bf16 Vs[64][72];
  const int tid = threadIdx.x;
  const int row = tid >> 2;
  const int c0  = (tid & 3) * 16;
  const long gin = ((long)(b * T_ + tt * 64 + row)) * D_ + h * HD_ + c0;
  *(bf16x8*)&Vs[row][c0]     = *(const bf16x8*)&v[gin];
  *(bf16x8*)&Vs[row][c0 + 8] = *(const bf16x8*)&v[gin + 8];
  __syncthreads();
  const int hd = tid >> 2;
  const int t0 = (tid & 3) * 16;
  bf16x8 o0, o1;
#pragma unroll
  for (int j = 0; j < 8; j++) { o0[j] = Vs[t0 + j][hd]; o1[j] = Vs[t0 + 8 + j][hd]; }
  const long gout = ((long)(bh * HD_ + hd)) * T_ + tt * 64 + t0;
  *(bf16x8*)&vt[gout]     = o0;
  *(bf16x8*)&vt[gout + 8] = o1;
}

// ---------------------------------------------------------------------------
// Flash attention, causal. Block = (bh, q-tile of 64). S^T = K Q^T; O^T = V^T P^T.
// ---------------------------------------------------------------------------
__global__ __launch_bounds__(256, 4)
void flash_attn(const bf16* __restrict__ q, const bf16* __restrict__ k,
                const bf16* __restrict__ vtg, bf16* __restrict__ y) {
  const int bh = blockIdx.x >> 5;
  const int qt = blockIdx.x & 31;
  const int b  = bh / H_;
  const int h  = bh % H_;
  const int q0 = qt * 64;

  __shared__ __align__(16) bf16 Qs[64][72];
  __shared__ __align__(16) bf16 Ks[64][72];
  __shared__ __align__(16) bf16 Vt[64][72];
  __shared__ __align__(16) bf16 Ps[4][16][72];

  const int tid = threadIdx.x, lane = tid & 63, w = tid >> 6;
  const int fr = lane & 15, quad = lane >> 4, fk = quad * 8;
  const long base = ((long)b * T_) * D_ + h * HD_;
  const long vbase = (long)bh * HD_ * T_;

  {
    const int srow = tid >> 2, scol = (tid & 3) * 16;
    const long g = base + (long)(q0 + srow) * D_ + scol;
    *(bf16x8*)&Qs[srow][scol]     = *(const bf16x8*)&q[g];
    *(bf16x8*)&Qs[srow][scol + 8] = *(const bf16x8*)&q[g + 8];
  }

  float m_st = -1e30f, l_st = 0.f;
  floatx4 o[4] = {};
  const float SC = 0.125f * LOG2E;

  for (int t = 0; t <= qt; t++) {
    const int k0 = t * 64;
    __syncthreads();
    {
      const int srow = tid >> 2, scol = (tid & 3) * 16;
      const long kg = base + (long)(k0 + srow) * D_ + scol;
      *(bf16x8*)&Ks[srow][scol]     = *(const bf16x8*)&k[kg];
      *(bf16x8*)&Ks[srow][scol + 8] = *(const bf16x8*)&k[kg + 8];
      const long vg = vbase + (long)srow * T_ + k0 + scol;
      *(bf16x8*)&Vt[srow][scol]     = *(const bf16x8*)&vtg[vg];
      *(bf16x8*)&Vt[srow][scol + 8] = *(const bf16x8*)&vtg[vg + 8];
    }
    __syncthreads();

    floatx4 s[4] = {};
#pragma unroll
    for (int kd = 0; kd < 2; kd++) {
      const bf16x8 bq = *(const bf16x8*)&Qs[w * 16 + fr][kd * 32 + fk];
#pragma unroll
      for (int kt = 0; kt < 4; kt++) {
        const bf16x8 ak = *(const bf16x8*)&Ks[kt * 16 + fr][kd * 32 + fk];
        s[kt] = mfma_bf16(ak, bq, s[kt]);
      }
    }

    if (t == qt) {
      const int qloc = w * 16 + fr;
#pragma unroll
      for (int kt = 0; kt < 4; kt++)
#pragma unroll
        for (int r = 0; r < 4; r++) {
          const int kvloc = kt * 16 + quad * 4 + r;
          s[kt][r] = (kvloc > qloc) ? -1e30f : s[kt][r] * SC;
        }
    } else {
#pragma unroll
      for (int kt = 0; kt < 4; kt++)
#pragma unroll
        for (int r = 0; r < 4; r++) s[kt][r] *= SC;
    }

    float mx = -1e30f;
#pragma unroll
    for (int kt = 0; kt < 4; kt++)
#pragma unroll
      for (int r = 0; r < 4; r++) mx = fmaxf(mx, s[kt][r]);
    mx = fmaxf(mx, __shfl_xor(mx, 16));
    mx = fmaxf(mx, __shfl_xor(mx, 32));
    const float mnew  = fmaxf(m_st, mx);
    const float alpha = exp2f(m_st - mnew);
    m_st = mnew;
    float rs = 0.f;
#pragma unroll
    for (int kt = 0; kt < 4; kt++)
#pragma unroll
      for (int r = 0; r < 4; r++) {
        const float pv = exp2f(s[kt][r] - mnew);
        s[kt][r] = pv;
        rs += pv;
      }
    rs += __shfl_xor(rs, 16);
    rs += __shfl_xor(rs, 32);
    l_st = l_st * alpha + rs;
#pragma unroll
    for (int ht = 0; ht < 4; ht++) o[ht] *= alpha;

#pragma unroll
    for (int kt = 0; kt < 4; kt++) {
      bf16x4 pk;
#pragma unroll
      for (int r = 0; r < 4; r++) pk[r] = (bf16)s[kt][r];
      *(bf16x4*)&Ps[w][fr][kt * 16 + quad * 4] = pk;
    }

#pragma unroll
    for (int kq = 0; kq < 2; kq++) {
      const bf16x8 bp = *(const bf16x8*)&Ps[w][fr][kq * 32 + fk];
#pragma unroll
      for (int ht = 0; ht < 4; ht++) {
        const bf16x8 av = *(const bf16x8*)&Vt[ht * 16 + fr][kq * 32 + fk];
        o[ht] = mfma_bf16(av, bp, o[ht]);
      }
    }
  }

  const float inv = 1.0f / l_st;
  const long yrow = base + (long)(q0 + w * 16 + fr) * D_;
#pragma unroll
  for (int ht = 0; ht < 4; ht++) {
    bf16x4 pk;
#pragma unroll
    for (int r = 0; r < 4; r++) pk[r] = (bf16)(o[ht][r] * inv);
    *(bf16x4*)&y[yrow + ht * 16 + quad * 4] = pk;
  }
}

// ---------------------------------------------------------------------------
// g1 = silu(g1) * g2, bf16 in-place.
// ---------------------------------------------------------------------------
__global__ __launch_bounds__(256)
void silu_mul_k(bf16* __restrict__ g1, const bf16* __restrict__ g2) {
  const long i0 = ((long)blockIdx.x * 256 + threadIdx.x) * 8;
  bf16x8 a = *(bf16x8*)&g1[i0];
  bf16x8 b = *(const bf16x8*)&g2[i0];
#pragma unroll
  for (int j = 0; j < 8; j++) {
    const float x = (float)a[j];
    const float s = x / (1.f + exp2f(-x * LOG2E));
    a[j] = (bf16)(s * (float)b[j]);
  }
  *(bf16x8*)&g1[i0] = a;
}

// ---------------------------------------------------------------------------
extern "C" void kernel_launch(void* const* d_in, const int* in_sizes, int n_in,
                              void* d_out, int out_size, void* d_ws, size_t ws_size,
                              hipStream_t stream) {
  const float* x    = (const float*)d_in[0];
  const float* wq   = (const float*)d_in[1];
  const float* wk   = (const float*)d_in[2];
  const float* wv   = (const float*)d_in[3];
  const float* wo   = (const float*)d_in[4];
  const float* w1   = (const float*)d_in[5];
  const float* w2   = (const float*)d_in[6];
  const float* w3   = (const float*)d_in[7];
  const float* anw  = (const float*)d_in[8];
  const float* fnw  = (const float*)d_in[9];
  const float* cosb = (const float*)d_in[10];
  const float* sinb = (const float*)d_in[11];

  char* ws = (char*)d_ws;
  bf16*  wb  = (bf16*)(ws + 0);
  bf16*  wqb = wb;
  bf16*  wkb = wb +  589824;
  bf16*  wvb = wb + 1179648;
  bf16*  wob = wb + 1769472;
  bf16*  w1b = wb + 2359296;
  bf16*  w2b = wb + 4718592;
  bf16*  w3b = wb + 7077888;
  bf16*  qb  = (bf16*)(ws + 18874368);
  bf16*  kb  = (bf16*)(ws + 25165824);
  bf16*  vb  = (bf16*)(ws + 31457280);
  bf16*  yb  = (bf16*)(ws + 37748736);
  bf16*  hn  = (bf16*)(ws + 44040192);
  float* xm  = (float*)(ws + 50331648);
  bf16*  g1  = (bf16*)(ws + 62914560);
  bf16*  vt  = (bf16*)(ws + 62914560);  // aliases g1 (dead before g1 written)
  bf16*  g2  = qb;                      // aliases dead q/k/v/y

  cvt_k<<<4608, 256, 0, stream>>>(wq, wk, wv, wo, w1, w2, w3, wb);
  rmsnorm_k<<<4096, 256, 0, stream>>>(x, anw, hn);
  gemm_qkv<<<dim3(18, 32), 256, 0, stream>>>(hn, wqb, wkb, wvb, qb, kb, vb);
  rope_k<<<6144, 256, 0, stream>>>(qb, kb, cosb, sinb);
  vtrans_k<<<768, 256, 0, stream>>>(vb, vt);
  flash_attn<<<768, 256, 0, stream>>>(qb, kb, vt, yb);
  gemm_n64<1><<<384, 256, 0, stream>>>(yb, wob, (void*)xm, x, 768, 768);
  rmsnorm_k<<<4096, 256, 0, stream>>>(xm, fnw, hn);
  gemm_bt<0><<<dim3(24, 32), 256, 0, stream>>>(hn, w1b, (void*)g1, nullptr, 3072, 768);
  gemm_bt<0><<<dim3(24, 32), 256, 0, stream>>>(hn, w2b, (void*)g2, nullptr, 3072, 768);
  silu_mul_k<<<6144, 256, 0, stream>>>(g1, g2);
  gemm_n64<1><<<384, 256, 0, stream>>>(g1, w3b, d_out, xm, 768, 3072);
}

// Round 6
// 322.025 us; speedup vs baseline: 1.4889x; 1.0790x over previous
//
#include <hip/hip_runtime.h>
#include <hip/hip_bf16.h>
#include <math.h>

typedef __bf16 bf16;
typedef __bf16 bf16x4 __attribute__((ext_vector_type(4)));
typedef __bf16 bf16x8 __attribute__((ext_vector_type(8)));
typedef float floatx4 __attribute__((ext_vector_type(4)));

#define T_ 2048
#define D_ 768
#define H_ 12
#define HD_ 64
#define FF_ 3072
#define LOG2E 1.44269504f
#define LDP 72   // padded LDS row stride (elems)

__device__ __forceinline__ floatx4 mfma_bf16(bf16x8 a, bf16x8 b, floatx4 c) {
  return __builtin_amdgcn_mfma_f32_16x16x32_bf16(a, b, c, 0, 0, 0);
}

// ---------------------------------------------------------------------------
// Convert the 7 fp32 weight matrices to bf16 (contiguous output buffer).
// ---------------------------------------------------------------------------
__global__ __launch_bounds__(256)
void cvt_k(const float* __restrict__ wq, const float* __restrict__ wk,
           const float* __restrict__ wv, const float* __restrict__ wo,
           const float* __restrict__ w1, const float* __restrict__ w2,
           const float* __restrict__ w3, bf16* __restrict__ o) {
  const long i = ((long)blockIdx.x * 256 + threadIdx.x) * 8;
  const float* s;
  if      (i <  589824) s = wq + i;
  else if (i < 1179648) s = wk + (i -  589824);
  else if (i < 1769472) s = wv + (i - 1179648);
  else if (i < 2359296) s = wo + (i - 1769472);
  else if (i < 4718592) s = w1 + (i - 2359296);
  else if (i < 7077888) s = w2 + (i - 4718592);
  else                  s = w3 + (i - 7077888);
  const floatx4 a = *(const floatx4*)s;
  const floatx4 b = *(const floatx4*)(s + 4);
  bf16x8 r;
#pragma unroll
  for (int j = 0; j < 4; j++) { r[j] = (bf16)a[j]; r[4 + j] = (bf16)b[j]; }
  *(bf16x8*)&o[i] = r;
}

// ---------------------------------------------------------------------------
// GEMM 128x128 tile, BK=64, register-prefetch pipeline (QKV only).
// ---------------------------------------------------------------------------
__device__ __forceinline__ void gemm128_core(
    const bf16* __restrict__ A, const bf16* __restrict__ W,
    bf16* __restrict__ C, int N, int K, int m0, int n0)
{
  __shared__ __align__(16) bf16 As[128 * LDP];
  __shared__ __align__(16) bf16 Ws[128 * LDP];

  const int tid = threadIdx.x;
  const int lane = tid & 63;
  const int wm = tid >> 7;
  const int wn = (tid >> 6) & 1;
  const int fr = lane & 15;
  const int fk = (lane >> 4) * 8;

  floatx4 acc[4][4] = {};

  const int ar = tid >> 3;
  const int ac = (tid & 7) * 8;
  const bf16* Aptr = A + (long)(m0 + ar) * K + ac;
  const bf16* Wptr = W + (long)(n0 + ar) * K + ac;
  const long rstep = (long)32 * K;

  bf16x8 apf[4], wpf[4];
#pragma unroll
  for (int c = 0; c < 4; c++) apf[c] = *(const bf16x8*)(Aptr + c * rstep);
#pragma unroll
  for (int c = 0; c < 4; c++) wpf[c] = *(const bf16x8*)(Wptr + c * rstep);

  const int ns = K >> 6;
  for (int ks = 0; ks < ns; ks++) {
    __syncthreads();
#pragma unroll
    for (int c = 0; c < 4; c++) *(bf16x8*)&As[(ar + c * 32) * LDP + ac] = apf[c];
#pragma unroll
    for (int c = 0; c < 4; c++) *(bf16x8*)&Ws[(ar + c * 32) * LDP + ac] = wpf[c];
    __syncthreads();
    const long koff = (long)((ks + 1 < ns) ? ks + 1 : ks) * 64;
#pragma unroll
    for (int c = 0; c < 4; c++) apf[c] = *(const bf16x8*)(Aptr + koff + c * rstep);
#pragma unroll
    for (int c = 0; c < 4; c++) wpf[c] = *(const bf16x8*)(Wptr + koff + c * rstep);
#pragma unroll
    for (int kc = 0; kc < 2; kc++) {
      bf16x8 af[4], bfv[4];
#pragma unroll
      for (int i = 0; i < 4; i++) af[i]  = *(const bf16x8*)&As[(wm * 64 + i * 16 + fr) * LDP + kc * 32 + fk];
#pragma unroll
      for (int j = 0; j < 4; j++) bfv[j] = *(const bf16x8*)&Ws[(wn * 64 + j * 16 + fr) * LDP + kc * 32 + fk];
#pragma unroll
      for (int i = 0; i < 4; i++)
#pragma unroll
        for (int j = 0; j < 4; j++)
          acc[i][j] = mfma_bf16(af[i], bfv[j], acc[i][j]);
    }
  }

  const int rb = (lane >> 4) * 4;
#pragma unroll
  for (int i = 0; i < 4; i++)
#pragma unroll
    for (int j = 0; j < 4; j++) {
      const int n = n0 + wn * 64 + j * 16 + fr;
#pragma unroll
      for (int r = 0; r < 4; r++) {
        const int m = m0 + wm * 64 + i * 16 + rb + r;
        C[(long)m * N + n] = (bf16)acc[i][j][r];
      }
    }
}

// QKV fused over N=2304: widx = blockIdx.x/6 picks weight/output.
__global__ __launch_bounds__(256)
void gemm_qkv(const bf16* __restrict__ h, const bf16* __restrict__ wq,
              const bf16* __restrict__ wk, const bf16* __restrict__ wv,
              bf16* __restrict__ q, bf16* __restrict__ k, bf16* __restrict__ v) {
  const int widx = blockIdx.x / 6;
  const int nb   = blockIdx.x % 6;
  const bf16* W = (widx == 0) ? wq : (widx == 1) ? wk : wv;
  bf16*       O = (widx == 0) ? q  : (widx == 1) ? k  : v;
  gemm128_core(h, W, O, D_, D_, blockIdx.y * 128, nb * 128);
}

// ---------------------------------------------------------------------------
// GEMM 128x64 tile for N=768 outputs (wo, w3). 384 blocks, XCD-swizzled.
// Epilogue: f32 C = acc + f32 resid.
// ---------------------------------------------------------------------------
__global__ __launch_bounds__(256)
void gemm_n64(const bf16* __restrict__ A, const bf16* __restrict__ W,
              float* __restrict__ C, const float* __restrict__ resid,
              int N, int K) {
  __shared__ __align__(16) bf16 As[128 * LDP];
  __shared__ __align__(16) bf16 Ws[64 * LDP];

  const int L  = blockIdx.x;
  const int j  = L >> 3;
  const int mb = (L & 7) * 4 + (j / 12);
  const int nb = j % 12;
  const int m0 = mb * 128, n0 = nb * 64;

  const int tid = threadIdx.x;
  const int lane = tid & 63;
  const int wm = tid >> 7;
  const int wn = (tid >> 6) & 1;
  const int fr = lane & 15;
  const int fk = (lane >> 4) * 8;

  floatx4 acc[4][2] = {};

  const int ar = tid >> 3;
  const int ac = (tid & 7) * 8;
  const bf16* Aptr = A + (long)(m0 + ar) * K + ac;
  const bf16* Wptr = W + (long)(n0 + ar) * K + ac;
  const long rstep = (long)32 * K;

  bf16x8 apf[4], wpf[2];
#pragma unroll
  for (int c = 0; c < 4; c++) apf[c] = *(const bf16x8*)(Aptr + c * rstep);
#pragma unroll
  for (int c = 0; c < 2; c++) wpf[c] = *(const bf16x8*)(Wptr + c * rstep);

  const int ns = K >> 6;
  for (int ks = 0; ks < ns; ks++) {
    __syncthreads();
#pragma unroll
    for (int c = 0; c < 4; c++) *(bf16x8*)&As[(ar + c * 32) * LDP + ac] = apf[c];
#pragma unroll
    for (int c = 0; c < 2; c++) *(bf16x8*)&Ws[(ar + c * 32) * LDP + ac] = wpf[c];
    __syncthreads();
    const long koff = (long)((ks + 1 < ns) ? ks + 1 : ks) * 64;
#pragma unroll
    for (int c = 0; c < 4; c++) apf[c] = *(const bf16x8*)(Aptr + koff + c * rstep);
#pragma unroll
    for (int c = 0; c < 2; c++) wpf[c] = *(const bf16x8*)(Wptr + koff + c * rstep);
#pragma unroll
    for (int kc = 0; kc < 2; kc++) {
      bf16x8 af[4], bfv[2];
#pragma unroll
      for (int i = 0; i < 4; i++) af[i]  = *(const bf16x8*)&As[(wm * 64 + i * 16 + fr) * LDP + kc * 32 + fk];
#pragma unroll
      for (int j2 = 0; j2 < 2; j2++) bfv[j2] = *(const bf16x8*)&Ws[(wn * 32 + j2 * 16 + fr) * LDP + kc * 32 + fk];
#pragma unroll
      for (int i = 0; i < 4; i++)
#pragma unroll
        for (int j2 = 0; j2 < 2; j2++)
          acc[i][j2] = mfma_bf16(af[i], bfv[j2], acc[i][j2]);
    }
  }

  const int rb = (lane >> 4) * 4;
#pragma unroll
  for (int i = 0; i < 4; i++)
#pragma unroll
    for (int j2 = 0; j2 < 2; j2++) {
      const int n = n0 + wn * 32 + j2 * 16 + fr;
#pragma unroll
      for (int r = 0; r < 4; r++) {
        const int m = m0 + wm * 64 + i * 16 + rb + r;
        const long idx = (long)m * N + n;
        C[idx] = acc[i][j2][r] + resid[idx];
      }
    }
}

// ---------------------------------------------------------------------------
// Fused w1/w2 GEMM + silu-mul epilogue. A [4096][768], W1,W2 [3072][768].
// G[m][n] = silu(A.W1^T) * (A.W2^T), bf16, N=3072. 1536 blocks, XCD-swizzled.
// ---------------------------------------------------------------------------
__global__ __launch_bounds__(256)
void gemm_w12(const bf16* __restrict__ A, const bf16* __restrict__ W1,
              const bf16* __restrict__ W2, bf16* __restrict__ G) {
  __shared__ __align__(16) bf16 As[128 * LDP];
  __shared__ __align__(16) bf16 W1s[64 * LDP];
  __shared__ __align__(16) bf16 W2s[64 * LDP];

  const int L  = blockIdx.x;
  const int j  = L >> 3;
  const int nb = (L & 7) * 6 + (j >> 5);   // 0..47
  const int mb = j & 31;
  const int m0 = mb * 128, n0 = nb * 64;
  const int K = D_;

  const int tid = threadIdx.x;
  const int lane = tid & 63;
  const int wm = tid >> 7;
  const int wn = (tid >> 6) & 1;
  const int fr = lane & 15;
  const int fk = (lane >> 4) * 8;

  floatx4 acc1[4][2] = {}, acc2[4][2] = {};

  const int ar = tid >> 3;
  const int ac = (tid & 7) * 8;
  const bf16* Aptr  = A  + (long)(m0 + ar) * K + ac;
  const bf16* W1ptr = W1 + (long)(n0 + ar) * K + ac;
  const bf16* W2ptr = W2 + (long)(n0 + ar) * K + ac;
  const long rstep = (long)32 * K;

  bf16x8 apf[4], w1pf[2], w2pf[2];
#pragma unroll
  for (int c = 0; c < 4; c++) apf[c] = *(const bf16x8*)(Aptr + c * rstep);
#pragma unroll
  for (int c = 0; c < 2; c++) { w1pf[c] = *(const bf16x8*)(W1ptr + c * rstep);
                                w2pf[c] = *(const bf16x8*)(W2ptr + c * rstep); }

  const int ns = K >> 6;   // 12
  for (int ks = 0; ks < ns; ks++) {
    __syncthreads();
#pragma unroll
    for (int c = 0; c < 4; c++) *(bf16x8*)&As[(ar + c * 32) * LDP + ac] = apf[c];
#pragma unroll
    for (int c = 0; c < 2; c++) { *(bf16x8*)&W1s[(ar + c * 32) * LDP + ac] = w1pf[c];
                                  *(bf16x8*)&W2s[(ar + c * 32) * LDP + ac] = w2pf[c]; }
    __syncthreads();
    const long koff = (long)((ks + 1 < ns) ? ks + 1 : ks) * 64;
#pragma unroll
    for (int c = 0; c < 4; c++) apf[c] = *(const bf16x8*)(Aptr + koff + c * rstep);
#pragma unroll
    for (int c = 0; c < 2; c++) { w1pf[c] = *(const bf16x8*)(W1ptr + koff + c * rstep);
                                  w2pf[c] = *(const bf16x8*)(W2ptr + koff + c * rstep); }
#pragma unroll
    for (int kc = 0; kc < 2; kc++) {
      bf16x8 af[4], b1[2], b2[2];
#pragma unroll
      for (int i = 0; i < 4; i++) af[i] = *(const bf16x8*)&As[(wm * 64 + i * 16 + fr) * LDP + kc * 32 + fk];
#pragma unroll
      for (int j2 = 0; j2 < 2; j2++) { b1[j2] = *(const bf16x8*)&W1s[(wn * 32 + j2 * 16 + fr) * LDP + kc * 32 + fk];
                                       b2[j2] = *(const bf16x8*)&W2s[(wn * 32 + j2 * 16 + fr) * LDP + kc * 32 + fk]; }
#pragma unroll
      for (int i = 0; i < 4; i++)
#pragma unroll
        for (int j2 = 0; j2 < 2; j2++) {
          acc1[i][j2] = mfma_bf16(af[i], b1[j2], acc1[i][j2]);
          acc2[i][j2] = mfma_bf16(af[i], b2[j2], acc2[i][j2]);
        }
    }
  }

  const int rb = (lane >> 4) * 4;
#pragma unroll
  for (int i = 0; i < 4; i++)
#pragma unroll
    for (int j2 = 0; j2 < 2; j2++) {
      const int n = n0 + wn * 32 + j2 * 16 + fr;
#pragma unroll
      for (int r = 0; r < 4; r++) {
        const int m = m0 + wm * 64 + i * 16 + rb + r;
        const float a1 = acc1[i][j2][r];
        const float a2 = acc2[i][j2][r];
        const float s = a1 / (1.f + exp2f(-a1 * LOG2E));
        G[(long)m * FF_ + n] = (bf16)(s * a2);
      }
    }
}

// ---------------------------------------------------------------------------
// RMSNorm: out_bf16 = w * x / (sqrt(mean(x^2)) + 1e-6); x, w fp32.
// ---------------------------------------------------------------------------
__global__ __launch_bounds__(256)
void rmsnorm_k(const float* __restrict__ x, const float* __restrict__ wt,
               bf16* __restrict__ o) {
  const int row = blockIdx.x;
  const int tid = threadIdx.x;
  const long off = (long)row * D_;
  float vals[3];
  float ss = 0.f;
#pragma unroll
  for (int i = 0; i < 3; i++) {
    vals[i] = x[off + tid + i * 256];
    ss += vals[i] * vals[i];
  }
#pragma unroll
  for (int d = 1; d < 64; d <<= 1) ss += __shfl_xor(ss, d);
  __shared__ float wsum[4];
  if ((tid & 63) == 0) wsum[tid >> 6] = ss;
  __syncthreads();
  const float tot = wsum[0] + wsum[1] + wsum[2] + wsum[3];
  const float inv = 1.0f / (sqrtf(tot * (1.0f / 768.0f)) + 1e-6f);
#pragma unroll
  for (int i = 0; i < 3; i++)
    o[off + tid + i * 256] = (bf16)(vals[i] * inv * wt[tid + i * 256]);
}

// ---------------------------------------------------------------------------
// RoPE in-place on bf16 q,k; cos/sin fp32 [2048][64] with c[2i]==c[2i+1].
// ---------------------------------------------------------------------------
__global__ __launch_bounds__(256)
void rope_k(bf16* __restrict__ q, bf16* __restrict__ k,
            const float* __restrict__ cosb, const float* __restrict__ sinb) {
  const int idx = blockIdx.x * 256 + threadIdx.x;
  const int tkn = idx / 384;
  const int p   = idx % 384;
  const int hh  = p >> 5;
  const int i   = p & 31;
  const int pos = tkn & (T_ - 1);
  const long off = (long)tkn * D_ + hh * HD_ + 2 * i;
  const float c0 = cosb[pos * HD_ + 2 * i];
  const float c1 = cosb[pos * HD_ + 2 * i + 1];
  const float s0 = sinb[pos * HD_ + 2 * i];
  const float s1 = sinb[pos * HD_ + 2 * i + 1];
  const float qe = (float)q[off], qo = (float)q[off + 1];
  q[off]     = (bf16)(qe * c0 - qo * s0);
  q[off + 1] = (bf16)(qo * c1 + qe * s1);
  const float ke = (float)k[off], ko = (float)k[off + 1];
  k[off]     = (bf16)(ke * c0 - ko * s0);
  k[off + 1] = (bf16)(ko * c1 + ke * s1);
}

// ---------------------------------------------------------------------------
// V transpose: v [b][t][h][hd] -> vt [b*H+h][hd][t]
// ---------------------------------------------------------------------------
__global__ __launch_bounds__(256)
void vtrans_k(const bf16* __restrict__ v, bf16* __restrict__ vt) {
  const int bh = blockIdx.x >> 5;
  const int tt = blockIdx.x & 31;
  const int b = bh / H_, h = bh % H_;
  __shared__ __align__(16) bf16 Vs[64][72];
  const int tid = threadIdx.x;
  const int row = tid >> 2;
  const int c0  = (tid & 3) * 16;
  const long gin = ((long)(b * T_ + tt * 64 + row)) * D_ + h * HD_ + c0;
  *(bf16x8*)&Vs[row][c0]     = *(const bf16x8*)&v[gin];
  *(bf16x8*)&Vs[row][c0 + 8] = *(const bf16x8*)&v[gin + 8];
  __syncthreads();
  const int hd = tid >> 2;
  const int t0 = (tid & 3) * 16;
  bf16x8 o0, o1;
#pragma unroll
  for (int j = 0; j < 8; j++) { o0[j] = Vs[t0 + j][hd]; o1[j] = Vs[t0 + 8 + j][hd]; }
  const long gout = ((long)(bh * HD_ + hd)) * T_ + tt * 64 + t0;
  *(bf16x8*)&vt[gout]     = o0;
  *(bf16x8*)&vt[gout + 8] = o1;
}

// ---------------------------------------------------------------------------
// Flash attention, split-K over KV. Block = (bh, qt, chunk). Chunk covers
// KV tiles [8c, min(8c+7, qt)] -> <=8 serial rounds. Writes partial O (fp32,
// [gid][q][hd]), m, l per q-row. 80 chunks/bh; grid 24*80 = 1920 blocks.
// ---------------------------------------------------------------------------
__global__ __launch_bounds__(256, 4)
void flash_attn(const bf16* __restrict__ q, const bf16* __restrict__ k,
                const bf16* __restrict__ vtg, float* __restrict__ po,
                float* __restrict__ pm, float* __restrict__ pl) {
  const int gid = blockIdx.x;
  const int bh = gid / 80;
  const int r  = gid % 80;
  int qt, c;
  if (r < 8)       { qt = r; c = 0; }
  else if (r < 24) { qt = 8 + ((r - 8) >> 1); c = (r - 8) & 1; }
  else if (r < 48) { const int u = r - 24; const int d = u / 3; qt = 16 + d; c = u - d * 3; }
  else             { const int u = r - 48; qt = 24 + (u >> 2); c = u & 3; }
  const int b  = bh / H_;
  const int h  = bh % H_;
  const int q0 = qt * 64;
  const int tbeg = c * 8;
  const int tend = (tbeg + 7 < qt) ? tbeg + 7 : qt;

  __shared__ __align__(16) bf16 Qs[64][72];
  __shared__ __align__(16) bf16 Ks[64][72];
  __shared__ __align__(16) bf16 Vt[64][72];
  __shared__ __align__(16) bf16 Ps[4][16][72];

  const int tid = threadIdx.x, lane = tid & 63, w = tid >> 6;
  const int fr = lane & 15, quad = lane >> 4, fk = quad * 8;
  const long base = ((long)b * T_) * D_ + h * HD_;
  const long vbase = (long)bh * HD_ * T_;

  {
    const int srow = tid >> 2, scol = (tid & 3) * 16;
    const long g = base + (long)(q0 + srow) * D_ + scol;
    *(bf16x8*)&Qs[srow][scol]     = *(const bf16x8*)&q[g];
    *(bf16x8*)&Qs[srow][scol + 8] = *(const bf16x8*)&q[g + 8];
  }

  float m_st = -1e30f, l_st = 0.f;
  floatx4 o[4] = {};
  const float SC = 0.125f * LOG2E;

  for (int t = tbeg; t <= tend; t++) {
    const int k0 = t * 64;
    __syncthreads();
    {
      const int srow = tid >> 2, scol = (tid & 3) * 16;
      const long kg = base + (long)(k0 + srow) * D_ + scol;
      *(bf16x8*)&Ks[srow][scol]     = *(const bf16x8*)&k[kg];
      *(bf16x8*)&Ks[srow][scol + 8] = *(const bf16x8*)&k[kg + 8];
      const long vg = vbase + (long)srow * T_ + k0 + scol;
      *(bf16x8*)&Vt[srow][scol]     = *(const bf16x8*)&vtg[vg];
      *(bf16x8*)&Vt[srow][scol + 8] = *(const bf16x8*)&vtg[vg + 8];
    }
    __syncthreads();

    floatx4 s[4] = {};
#pragma unroll
    for (int kd = 0; kd < 2; kd++) {
      const bf16x8 bq = *(const bf16x8*)&Qs[w * 16 + fr][kd * 32 + fk];
#pragma unroll
      for (int kt = 0; kt < 4; kt++) {
        const bf16x8 ak = *(const bf16x8*)&Ks[kt * 16 + fr][kd * 32 + fk];
        s[kt] = mfma_bf16(ak, bq, s[kt]);
      }
    }

    if (t == qt) {
      const int qloc = w * 16 + fr;
#pragma unroll
      for (int kt = 0; kt < 4; kt++)
#pragma unroll
        for (int r2 = 0; r2 < 4; r2++) {
          const int kvloc = kt * 16 + quad * 4 + r2;
          s[kt][r2] = (kvloc > qloc) ? -1e30f : s[kt][r2] * SC;
        }
    } else {
#pragma unroll
      for (int kt = 0; kt < 4; kt++)
#pragma unroll
        for (int r2 = 0; r2 < 4; r2++) s[kt][r2] *= SC;
    }

    float mx = -1e30f;
#pragma unroll
    for (int kt = 0; kt < 4; kt++)
#pragma unroll
      for (int r2 = 0; r2 < 4; r2++) mx = fmaxf(mx, s[kt][r2]);
    mx = fmaxf(mx, __shfl_xor(mx, 16));
    mx = fmaxf(mx, __shfl_xor(mx, 32));
    const float mnew  = fmaxf(m_st, mx);
    const float alpha = exp2f(m_st - mnew);
    m_st = mnew;
    float rs = 0.f;
#pragma unroll
    for (int kt = 0; kt < 4; kt++)
#pragma unroll
      for (int r2 = 0; r2 < 4; r2++) {
        const float pv = exp2f(s[kt][r2] - mnew);
        s[kt][r2] = pv;
        rs += pv;
      }
    rs += __shfl_xor(rs, 16);
    rs += __shfl_xor(rs, 32);
    l_st = l_st * alpha + rs;
#pragma unroll
    for (int ht = 0; ht < 4; ht++) o[ht] *= alpha;

#pragma unroll
    for (int kt = 0; kt < 4; kt++) {
      bf16x4 pk;
#pragma unroll
      for (int r2 = 0; r2 < 4; r2++) pk[r2] = (bf16)s[kt][r2];
      *(bf16x4*)&Ps[w][fr][kt * 16 + quad * 4] = pk;
    }

#pragma unroll
    for (int kq = 0; kq < 2; kq++) {
      const bf16x8 bp = *(const bf16x8*)&Ps[w][fr][kq * 32 + fk];
#pragma unroll
      for (int ht = 0; ht < 4; ht++) {
        const bf16x8 av = *(const bf16x8*)&Vt[ht * 16 + fr][kq * 32 + fk];
        o[ht] = mfma_bf16(av, bp, o[ht]);
      }
    }
  }

  // store partials: po[gid][q][hd] fp32, pm/pl[gid][q]
  const int qq = w * 16 + fr;
  const long pg = (long)gid * 4096 + qq * 64;
#pragma unroll
  for (int ht = 0; ht < 4; ht++)
    *(floatx4*)&po[pg + ht * 16 + quad * 4] = o[ht];
  if (quad == 0) { pm[gid * 64 + qq] = m_st; pl[gid * 64 + qq] = l_st; }
}

// ---------------------------------------------------------------------------
// Combine split-K partials: block = (bh, qt), 768 blocks.
// ---------------------------------------------------------------------------
__global__ __launch_bounds__(256)
void flash_comb(const float* __restrict__ po, const float* __restrict__ pm,
                const float* __restrict__ pl, bf16* __restrict__ y) {
  const int bh = blockIdx.x >> 5;
  const int qt = blockIdx.x & 31;
  const int b = bh / H_, h = bh % H_;
  const int nc = (qt >> 3) + 1;
  int bse;
  if      (qt <  8) bse = qt;
  else if (qt < 16) bse = 8  + 2 * (qt - 8);
  else if (qt < 24) bse = 24 + 3 * (qt - 16);
  else              bse = 48 + 4 * (qt - 24);
  const int g0 = bh * 80 + bse;

  const int t = threadIdx.x;
  const int qq = t >> 2, hg = (t & 3) * 16;

  float M = -1e30f;
  for (int c2 = 0; c2 < nc; c2++) M = fmaxf(M, pm[(g0 + c2) * 64 + qq]);
  float l = 0.f;
  floatx4 o[4] = {};
  for (int c2 = 0; c2 < nc; c2++) {
    const float wgt = exp2f(pm[(g0 + c2) * 64 + qq] - M);
    l += wgt * pl[(g0 + c2) * 64 + qq];
    const long pg = (long)(g0 + c2) * 4096 + qq * 64 + hg;
#pragma unroll
    for (int j = 0; j < 4; j++) {
      const floatx4 t4 = *(const floatx4*)&po[pg + j * 4];
#pragma unroll
      for (int e = 0; e < 4; e++) o[j][e] += wgt * t4[e];
    }
  }
  const float inv = 1.f / l;
  bf16x8 r0, r1;
#pragma unroll
  for (int e = 0; e < 4; e++) {
    r0[e]     = (bf16)(o[0][e] * inv);
    r0[4 + e] = (bf16)(o[1][e] * inv);
    r1[e]     = (bf16)(o[2][e] * inv);
    r1[4 + e] = (bf16)(o[3][e] * inv);
  }
  const long yoff = ((long)b * T_ + qt * 64 + qq) * D_ + h * HD_ + hg;
  *(bf16x8*)&y[yoff]     = r0;
  *(bf16x8*)&y[yoff + 8] = r1;
}

// ---------------------------------------------------------------------------
extern "C" void kernel_launch(void* const* d_in, const int* in_sizes, int n_in,
                              void* d_out, int out_size, void* d_ws, size_t ws_size,
                              hipStream_t stream) {
  const float* x    = (const float*)d_in[0];
  const float* wq   = (const float*)d_in[1];
  const float* wk   = (const float*)d_in[2];
  const float* wv   = (const float*)d_in[3];
  const float* wo   = (const float*)d_in[4];
  const float* w1   = (const float*)d_in[5];
  const float* w2   = (const float*)d_in[6];
  const float* w3   = (const float*)d_in[7];
  const float* anw  = (const float*)d_in[8];
  const float* fnw  = (const float*)d_in[9];
  const float* cosb = (const float*)d_in[10];
  const float* sinb = (const float*)d_in[11];

  char* ws = (char*)d_ws;
  // Layout (bytes), total 88,080,384. Lifetimes allow aliasing:
  //   vb (qkv->vtrans) and po/pm/pl (flash->comb) overlay xm/g (written later).
  bf16*  wb  = (bf16*)(ws + 0);                // 18,874,368
  bf16*  wqb = wb;
  bf16*  wkb = wb +  589824;
  bf16*  wvb = wb + 1179648;
  bf16*  wob = wb + 1769472;
  bf16*  w1b = wb + 2359296;
  bf16*  w2b = wb + 4718592;
  bf16*  w3b = wb + 7077888;
  bf16*  qb  = (bf16*)(ws + 18874368);
  bf16*  kb  = (bf16*)(ws + 25165824);
  bf16*  vt  = (bf16*)(ws + 31457280);
  bf16*  yb  = (bf16*)(ws + 37748736);
  bf16*  hn  = (bf16*)(ws + 44040192);
  float* xm  = (float*)(ws + 50331648);        // 12,582,912
  bf16*  g   = (bf16*)(ws + 62914560);         // 25,165,824
  bf16*  vb  = (bf16*)(ws + 62914560);         // aliases g head (dead before g)
  float* po  = (float*)(ws + 50331648);        // 31,457,280 (aliases xm+g head)
  float* pm  = (float*)(ws + 81788928);        //    491,520
  float* pl  = (float*)(ws + 82280448);        //    491,520

  cvt_k<<<4608, 256, 0, stream>>>(wq, wk, wv, wo, w1, w2, w3, wb);
  rmsnorm_k<<<4096, 256, 0, stream>>>(x, anw, hn);
  gemm_qkv<<<dim3(18, 32), 256, 0, stream>>>(hn, wqb, wkb, wvb, qb, kb, vb);
  rope_k<<<6144, 256, 0, stream>>>(qb, kb, cosb, sinb);
  vtrans_k<<<768, 256, 0, stream>>>(vb, vt);
  flash_attn<<<1920, 256, 0, stream>>>(qb, kb, vt, po, pm, pl);
  flash_comb<<<768, 256, 0, stream>>>(po, pm, pl, yb);
  gemm_n64<<<384, 256, 0, stream>>>(yb, wob, xm, x, 768, 768);
  rmsnorm_k<<<4096, 256, 0, stream>>>(xm, fnw, hn);
  gemm_w12<<<1536, 256, 0, stream>>>(hn, w1b, w2b, g);
  gemm_n64<<<384, 256, 0, stream>>>(g, w3b, (float*)d_out, xm, 768, 3072);
}

// Round 7
// 308.774 us; speedup vs baseline: 1.5528x; 1.0429x over previous
//
#include <hip/hip_runtime.h>
#include <hip/hip_bf16.h>
#include <math.h>

typedef __bf16 bf16;
typedef __bf16 bf16x4 __attribute__((ext_vector_type(4)));
typedef __bf16 bf16x8 __attribute__((ext_vector_type(8)));
typedef float floatx4 __attribute__((ext_vector_type(4)));

#define T_ 2048
#define D_ 768
#define H_ 12
#define HD_ 64
#define FF_ 3072
#define LOG2E 1.44269504f
#define LDP 72   // padded LDS row stride (elems)

__device__ __forceinline__ floatx4 mfma_bf16(bf16x8 a, bf16x8 b, floatx4 c) {
  return __builtin_amdgcn_mfma_f32_16x16x32_bf16(a, b, c, 0, 0, 0);
}

// ---------------------------------------------------------------------------
// Convert the 7 fp32 weight matrices to bf16 (contiguous output buffer).
// ---------------------------------------------------------------------------
__global__ __launch_bounds__(256)
void cvt_k(const float* __restrict__ wq, const float* __restrict__ wk,
           const float* __restrict__ wv, const float* __restrict__ wo,
           const float* __restrict__ w1, const float* __restrict__ w2,
           const float* __restrict__ w3, bf16* __restrict__ o) {
  const long i = ((long)blockIdx.x * 256 + threadIdx.x) * 8;
  const float* s;
  if      (i <  589824) s = wq + i;
  else if (i < 1179648) s = wk + (i -  589824);
  else if (i < 1769472) s = wv + (i - 1179648);
  else if (i < 2359296) s = wo + (i - 1769472);
  else if (i < 4718592) s = w1 + (i - 2359296);
  else if (i < 7077888) s = w2 + (i - 4718592);
  else                  s = w3 + (i - 7077888);
  const floatx4 a = *(const floatx4*)s;
  const floatx4 b = *(const floatx4*)(s + 4);
  bf16x8 r;
#pragma unroll
  for (int j = 0; j < 4; j++) { r[j] = (bf16)a[j]; r[4 + j] = (bf16)b[j]; }
  *(bf16x8*)&o[i] = r;
}

// ---------------------------------------------------------------------------
// Fused QKV GEMM, 128x128 tile, BK=64, register-prefetch. Epilogue:
//   widx 0/1 (q,k): RoPE applied in-register (shfl_xor pair exchange).
//   widx 2   (v)  : store transposed directly to vt[bh][hd][t] (bf16x4).
// ---------------------------------------------------------------------------
__global__ __launch_bounds__(256)
void gemm_qkv(const bf16* __restrict__ A, const bf16* __restrict__ wq,
              const bf16* __restrict__ wk, const bf16* __restrict__ wv,
              bf16* __restrict__ q, bf16* __restrict__ k, bf16* __restrict__ vt,
              const float* __restrict__ cosb, const float* __restrict__ sinb) {
  const int widx = blockIdx.x / 6;
  const int nb   = blockIdx.x % 6;
  const bf16* W = (widx == 0) ? wq : (widx == 1) ? wk : wv;
  const int m0 = blockIdx.y * 128, n0 = nb * 128;
  const int K = D_;

  __shared__ __align__(16) bf16 As[128 * LDP];
  __shared__ __align__(16) bf16 Ws[128 * LDP];

  const int tid = threadIdx.x;
  const int lane = tid & 63;
  const int wm = tid >> 7;
  const int wn = (tid >> 6) & 1;
  const int fr = lane & 15;
  const int fk = (lane >> 4) * 8;

  floatx4 acc[4][4] = {};

  const int ar = tid >> 3;
  const int ac = (tid & 7) * 8;
  const bf16* Aptr = A + (long)(m0 + ar) * K + ac;
  const bf16* Wptr = W + (long)(n0 + ar) * K + ac;
  const long rstep = (long)32 * K;

  bf16x8 apf[4], wpf[4];
#pragma unroll
  for (int c = 0; c < 4; c++) apf[c] = *(const bf16x8*)(Aptr + c * rstep);
#pragma unroll
  for (int c = 0; c < 4; c++) wpf[c] = *(const bf16x8*)(Wptr + c * rstep);

  const int ns = K >> 6;   // 12
  for (int ks = 0; ks < ns; ks++) {
    __syncthreads();
#pragma unroll
    for (int c = 0; c < 4; c++) *(bf16x8*)&As[(ar + c * 32) * LDP + ac] = apf[c];
#pragma unroll
    for (int c = 0; c < 4; c++) *(bf16x8*)&Ws[(ar + c * 32) * LDP + ac] = wpf[c];
    __syncthreads();
    const long koff = (long)((ks + 1 < ns) ? ks + 1 : ks) * 64;
#pragma unroll
    for (int c = 0; c < 4; c++) apf[c] = *(const bf16x8*)(Aptr + koff + c * rstep);
#pragma unroll
    for (int c = 0; c < 4; c++) wpf[c] = *(const bf16x8*)(Wptr + koff + c * rstep);
#pragma unroll
    for (int kc = 0; kc < 2; kc++) {
      bf16x8 af[4], bfv[4];
#pragma unroll
      for (int i = 0; i < 4; i++) af[i]  = *(const bf16x8*)&As[(wm * 64 + i * 16 + fr) * LDP + kc * 32 + fk];
#pragma unroll
      for (int j = 0; j < 4; j++) bfv[j] = *(const bf16x8*)&Ws[(wn * 64 + j * 16 + fr) * LDP + kc * 32 + fk];
#pragma unroll
      for (int i = 0; i < 4; i++)
#pragma unroll
        for (int j = 0; j < 4; j++)
          acc[i][j] = mfma_bf16(af[i], bfv[j], acc[i][j]);
    }
  }

  const int rb = (lane >> 4) * 4;
  if (widx < 2) {
    // RoPE epilogue. n parity = fr parity; partner value in lane^1 (same quad).
    bf16* O = (widx == 0) ? q : k;
    const float sgn = (fr & 1) ? 1.f : -1.f;
#pragma unroll
    for (int i = 0; i < 4; i++)
#pragma unroll
      for (int j = 0; j < 4; j++) {
        const int n = n0 + wn * 64 + j * 16 + fr;
        const int d = n & 63;
#pragma unroll
        for (int r = 0; r < 4; r++) {
          const int m = m0 + wm * 64 + i * 16 + rb + r;
          const int pos = m & (T_ - 1);
          const float val = acc[i][j][r];
          const float par = __shfl_xor(val, 1);
          const float cc = cosb[pos * HD_ + d];
          const float ss = sinb[pos * HD_ + d];
          O[(long)m * D_ + n] = (bf16)(val * cc + sgn * par * ss);
        }
      }
  } else {
    // V^T epilogue: vt[(b*12 + n/64)*64 + (n&63)][t], 4 consecutive t per reg.
#pragma unroll
    for (int i = 0; i < 4; i++)
#pragma unroll
      for (int j = 0; j < 4; j++) {
        const int n = n0 + wn * 64 + j * 16 + fr;
        const int m = m0 + wm * 64 + i * 16 + rb;
        const int b = m >> 11;
        const int t = m & (T_ - 1);
        const long row = (long)(b * H_ + (n >> 6)) * HD_ + (n & 63);
        bf16x4 pk;
#pragma unroll
        for (int r = 0; r < 4; r++) pk[r] = (bf16)acc[i][j][r];
        *(bf16x4*)&vt[row * T_ + t] = pk;
      }
  }
}

// ---------------------------------------------------------------------------
// GEMM 128x64 tile for wo (N=768, K=768). 384 blocks, XCD-swizzled.
// Epilogue: f32 C = acc + f32 resid.
// ---------------------------------------------------------------------------
__global__ __launch_bounds__(256)
void gemm_n64(const bf16* __restrict__ A, const bf16* __restrict__ W,
              float* __restrict__ C, const float* __restrict__ resid,
              int N, int K) {
  __shared__ __align__(16) bf16 As[128 * LDP];
  __shared__ __align__(16) bf16 Ws[64 * LDP];

  const int L  = blockIdx.x;
  const int j  = L >> 3;
  const int mb = (L & 7) * 4 + (j / 12);
  const int nb = j % 12;
  const int m0 = mb * 128, n0 = nb * 64;

  const int tid = threadIdx.x;
  const int lane = tid & 63;
  const int wm = tid >> 7;
  const int wn = (tid >> 6) & 1;
  const int fr = lane & 15;
  const int fk = (lane >> 4) * 8;

  floatx4 acc[4][2] = {};

  const int ar = tid >> 3;
  const int ac = (tid & 7) * 8;
  const bf16* Aptr = A + (long)(m0 + ar) * K + ac;
  const bf16* Wptr = W + (long)(n0 + ar) * K + ac;
  const long rstep = (long)32 * K;

  bf16x8 apf[4], wpf[2];
#pragma unroll
  for (int c = 0; c < 4; c++) apf[c] = *(const bf16x8*)(Aptr + c * rstep);
#pragma unroll
  for (int c = 0; c < 2; c++) wpf[c] = *(const bf16x8*)(Wptr + c * rstep);

  const int ns = K >> 6;
  for (int ks = 0; ks < ns; ks++) {
    __syncthreads();
#pragma unroll
    for (int c = 0; c < 4; c++) *(bf16x8*)&As[(ar + c * 32) * LDP + ac] = apf[c];
#pragma unroll
    for (int c = 0; c < 2; c++) *(bf16x8*)&Ws[(ar + c * 32) * LDP + ac] = wpf[c];
    __syncthreads();
    const long koff = (long)((ks + 1 < ns) ? ks + 1 : ks) * 64;
#pragma unroll
    for (int c = 0; c < 4; c++) apf[c] = *(const bf16x8*)(Aptr + koff + c * rstep);
#pragma unroll
    for (int c = 0; c < 2; c++) wpf[c] = *(const bf16x8*)(Wptr + koff + c * rstep);
#pragma unroll
    for (int kc = 0; kc < 2; kc++) {
      bf16x8 af[4], bfv[2];
#pragma unroll
      for (int i = 0; i < 4; i++) af[i]  = *(const bf16x8*)&As[(wm * 64 + i * 16 + fr) * LDP + kc * 32 + fk];
#pragma unroll
      for (int j2 = 0; j2 < 2; j2++) bfv[j2] = *(const bf16x8*)&Ws[(wn * 32 + j2 * 16 + fr) * LDP + kc * 32 + fk];
#pragma unroll
      for (int i = 0; i < 4; i++)
#pragma unroll
        for (int j2 = 0; j2 < 2; j2++)
          acc[i][j2] = mfma_bf16(af[i], bfv[j2], acc[i][j2]);
    }
  }

  const int rb = (lane >> 4) * 4;
#pragma unroll
  for (int i = 0; i < 4; i++)
#pragma unroll
    for (int j2 = 0; j2 < 2; j2++) {
      const int n = n0 + wn * 32 + j2 * 16 + fr;
#pragma unroll
      for (int r = 0; r < 4; r++) {
        const int m = m0 + wm * 64 + i * 16 + rb + r;
        const long idx = (long)m * N + n;
        C[idx] = acc[i][j2][r] + resid[idx];
      }
    }
}

// ---------------------------------------------------------------------------
// w3 GEMM, split-K x2: 768 blocks, each does K-half of 1536 (24 steps).
// s=0 -> p0, s=1 -> p1 (fp32 partials, no residual). Per-XCD: 4 m-stripes,
// s outer of nb so the A half-slice (96 KB) stays L2-resident over 12 nb.
// ---------------------------------------------------------------------------
__global__ __launch_bounds__(256)
void gemm_w3sk(const bf16* __restrict__ A, const bf16* __restrict__ W,
               float* __restrict__ p0, float* __restrict__ p1) {
  __shared__ __align__(16) bf16 As[128 * LDP];
  __shared__ __align__(16) bf16 Ws[64 * LDP];

  const int L  = blockIdx.x;
  const int j  = L >> 3;                  // 0..95
  const int mb = (L & 7) * 4 + (j / 24);
  const int inner = j % 24;
  const int s  = inner / 12;
  const int nb = inner % 12;
  const int m0 = mb * 128, n0 = nb * 64;
  const int K = FF_;
  const int kbase = s * 1536;
  float* C = s ? p1 : p0;

  const int tid = threadIdx.x;
  const int lane = tid & 63;
  const int wm = tid >> 7;
  const int wn = (tid >> 6) & 1;
  const int fr = lane & 15;
  const int fk = (lane >> 4) * 8;

  floatx4 acc[4][2] = {};

  const int ar = tid >> 3;
  const int ac = (tid & 7) * 8;
  const bf16* Aptr = A + (long)(m0 + ar) * K + kbase + ac;
  const bf16* Wptr = W + (long)(n0 + ar) * K + kbase + ac;
  const long rstep = (long)32 * K;

  bf16x8 apf[4], wpf[2];
#pragma unroll
  for (int c = 0; c < 4; c++) apf[c] = *(const bf16x8*)(Aptr + c * rstep);
#pragma unroll
  for (int c = 0; c < 2; c++) wpf[c] = *(const bf16x8*)(Wptr + c * rstep);

  const int ns = 24;
  for (int ks = 0; ks < ns; ks++) {
    __syncthreads();
#pragma unroll
    for (int c = 0; c < 4; c++) *(bf16x8*)&As[(ar + c * 32) * LDP + ac] = apf[c];
#pragma unroll
    for (int c = 0; c < 2; c++) *(bf16x8*)&Ws[(ar + c * 32) * LDP + ac] = wpf[c];
    __syncthreads();
    const long koff = (long)((ks + 1 < ns) ? ks + 1 : ks) * 64;
#pragma unroll
    for (int c = 0; c < 4; c++) apf[c] = *(const bf16x8*)(Aptr + koff + c * rstep);
#pragma unroll
    for (int c = 0; c < 2; c++) wpf[c] = *(const bf16x8*)(Wptr + koff + c * rstep);
#pragma unroll
    for (int kc = 0; kc < 2; kc++) {
      bf16x8 af[4], bfv[2];
#pragma unroll
      for (int i = 0; i < 4; i++) af[i]  = *(const bf16x8*)&As[(wm * 64 + i * 16 + fr) * LDP + kc * 32 + fk];
#pragma unroll
      for (int j2 = 0; j2 < 2; j2++) bfv[j2] = *(const bf16x8*)&Ws[(wn * 32 + j2 * 16 + fr) * LDP + kc * 32 + fk];
#pragma unroll
      for (int i = 0; i < 4; i++)
#pragma unroll
        for (int j2 = 0; j2 < 2; j2++)
          acc[i][j2] = mfma_bf16(af[i], bfv[j2], acc[i][j2]);
    }
  }

  const int rb = (lane >> 4) * 4;
#pragma unroll
  for (int i = 0; i < 4; i++)
#pragma unroll
    for (int j2 = 0; j2 < 2; j2++) {
      const int n = n0 + wn * 32 + j2 * 16 + fr;
#pragma unroll
      for (int r = 0; r < 4; r++) {
        const int m = m0 + wm * 64 + i * 16 + rb + r;
        C[(long)m * D_ + n] = acc[i][j2][r];
      }
    }
}

// out = p0 + p1 + xm (fp32), 3.1M elems, 8/thread.
__global__ __launch_bounds__(256)
void comb3_k(const float* __restrict__ p0, const float* __restrict__ p1,
             const float* __restrict__ xm, float* __restrict__ out) {
  const long i = ((long)blockIdx.x * 256 + threadIdx.x) * 8;
#pragma unroll
  for (int c = 0; c < 2; c++) {
    const floatx4 a = *(const floatx4*)&p0[i + c * 4];
    const floatx4 b = *(const floatx4*)&p1[i + c * 4];
    const floatx4 d = *(const floatx4*)&xm[i + c * 4];
    floatx4 r;
#pragma unroll
    for (int e = 0; e < 4; e++) r[e] = a[e] + b[e] + d[e];
    *(floatx4*)&out[i + c * 4] = r;
  }
}

// ---------------------------------------------------------------------------
// Fused w1/w2 GEMM + silu-mul epilogue. 1536 blocks, XCD-swizzled with mb
// outer per XCD (A-slice 196 KB stays L2-resident across its 6 n-stripes).
// ---------------------------------------------------------------------------
__global__ __launch_bounds__(256)
void gemm_w12(const bf16* __restrict__ A, const bf16* __restrict__ W1,
              const bf16* __restrict__ W2, bf16* __restrict__ G) {
  __shared__ __align__(16) bf16 As[128 * LDP];
  __shared__ __align__(16) bf16 W1s[64 * LDP];
  __shared__ __align__(16) bf16 W2s[64 * LDP];

  const int L  = blockIdx.x;
  const int j  = L >> 3;                  // 0..191
  const int mb = j / 6;                   // 0..31 (outer per XCD)
  const int nb = (L & 7) * 6 + (j % 6);   // 0..47
  const int m0 = mb * 128, n0 = nb * 64;
  const int K = D_;

  const int tid = threadIdx.x;
  const int lane = tid & 63;
  const int wm = tid >> 7;
  const int wn = (tid >> 6) & 1;
  const int fr = lane & 15;
  const int fk = (lane >> 4) * 8;

  floatx4 acc1[4][2] = {}, acc2[4][2] = {};

  const int ar = tid >> 3;
  const int ac = (tid & 7) * 8;
  const bf16* Aptr  = A  + (long)(m0 + ar) * K + ac;
  const bf16* W1ptr = W1 + (long)(n0 + ar) * K + ac;
  const bf16* W2ptr = W2 + (long)(n0 + ar) * K + ac;
  const long rstep = (long)32 * K;

  bf16x8 apf[4], w1pf[2], w2pf[2];
#pragma unroll
  for (int c = 0; c < 4; c++) apf[c] = *(const bf16x8*)(Aptr + c * rstep);
#pragma unroll
  for (int c = 0; c < 2; c++) { w1pf[c] = *(const bf16x8*)(W1ptr + c * rstep);
                                w2pf[c] = *(const bf16x8*)(W2ptr + c * rstep); }

  const int ns = K >> 6;   // 12
  for (int ks = 0; ks < ns; ks++) {
    __syncthreads();
#pragma unroll
    for (int c = 0; c < 4; c++) *(bf16x8*)&As[(ar + c * 32) * LDP + ac] = apf[c];
#pragma unroll
    for (int c = 0; c < 2; c++) { *(bf16x8*)&W1s[(ar + c * 32) * LDP + ac] = w1pf[c];
                                  *(bf16x8*)&W2s[(ar + c * 32) * LDP + ac] = w2pf[c]; }
    __syncthreads();
    const long koff = (long)((ks + 1 < ns) ? ks + 1 : ks) * 64;
#pragma unroll
    for (int c = 0; c < 4; c++) apf[c] = *(const bf16x8*)(Aptr + koff + c * rstep);
#pragma unroll
    for (int c = 0; c < 2; c++) { w1pf[c] = *(const bf16x8*)(W1ptr + koff + c * rstep);
                                  w2pf[c] = *(const bf16x8*)(W2ptr + koff + c * rstep); }
#pragma unroll
    for (int kc = 0; kc < 2; kc++) {
      bf16x8 af[4], b1[2], b2[2];
#pragma unroll
      for (int i = 0; i < 4; i++) af[i] = *(const bf16x8*)&As[(wm * 64 + i * 16 + fr) * LDP + kc * 32 + fk];
#pragma unroll
      for (int j2 = 0; j2 < 2; j2++) { b1[j2] = *(const bf16x8*)&W1s[(wn * 32 + j2 * 16 + fr) * LDP + kc * 32 + fk];
                                       b2[j2] = *(const bf16x8*)&W2s[(wn * 32 + j2 * 16 + fr) * LDP + kc * 32 + fk]; }
#pragma unroll
      for (int i = 0; i < 4; i++)
#pragma unroll
        for (int j2 = 0; j2 < 2; j2++) {
          acc1[i][j2] = mfma_bf16(af[i], b1[j2], acc1[i][j2]);
          acc2[i][j2] = mfma_bf16(af[i], b2[j2], acc2[i][j2]);
        }
    }
  }

  const int rb = (lane >> 4) * 4;
#pragma unroll
  for (int i = 0; i < 4; i++)
#pragma unroll
    for (int j2 = 0; j2 < 2; j2++) {
      const int n = n0 + wn * 32 + j2 * 16 + fr;
#pragma unroll
      for (int r = 0; r < 4; r++) {
        const int m = m0 + wm * 64 + i * 16 + rb + r;
        const float a1 = acc1[i][j2][r];
        const float a2 = acc2[i][j2][r];
        const float s = a1 / (1.f + exp2f(-a1 * LOG2E));
        G[(long)m * FF_ + n] = (bf16)(s * a2);
      }
    }
}

// ---------------------------------------------------------------------------
// RMSNorm: out_bf16 = w * x / (sqrt(mean(x^2)) + 1e-6); x, w fp32.
// ---------------------------------------------------------------------------
__global__ __launch_bounds__(256)
void rmsnorm_k(const float* __restrict__ x, const float* __restrict__ wt,
               bf16* __restrict__ o) {
  const int row = blockIdx.x;
  const int tid = threadIdx.x;
  const long off = (long)row * D_;
  float vals[3];
  float ss = 0.f;
#pragma unroll
  for (int i = 0; i < 3; i++) {
    vals[i] = x[off + tid + i * 256];
    ss += vals[i] * vals[i];
  }
#pragma unroll
  for (int d = 1; d < 64; d <<= 1) ss += __shfl_xor(ss, d);
  __shared__ float wsum[4];
  if ((tid & 63) == 0) wsum[tid >> 6] = ss;
  __syncthreads();
  const float tot = wsum[0] + wsum[1] + wsum[2] + wsum[3];
  const float inv = 1.0f / (sqrtf(tot * (1.0f / 768.0f)) + 1e-6f);
#pragma unroll
  for (int i = 0; i < 3; i++)
    o[off + tid + i * 256] = (bf16)(vals[i] * inv * wt[tid + i * 256]);
}

// ---------------------------------------------------------------------------
// Flash attention, split-K over KV. Block = (bh, qt, chunk), <=8 rounds.
// ---------------------------------------------------------------------------
__global__ __launch_bounds__(256, 4)
void flash_attn(const bf16* __restrict__ q, const bf16* __restrict__ k,
                const bf16* __restrict__ vtg, float* __restrict__ po,
                float* __restrict__ pm, float* __restrict__ pl) {
  const int gid = blockIdx.x;
  const int bh = gid / 80;
  const int r  = gid % 80;
  int qt, c;
  if (r < 8)       { qt = r; c = 0; }
  else if (r < 24) { qt = 8 + ((r - 8) >> 1); c = (r - 8) & 1; }
  else if (r < 48) { const int u = r - 24; const int d = u / 3; qt = 16 + d; c = u - d * 3; }
  else             { const int u = r - 48; qt = 24 + (u >> 2); c = u & 3; }
  const int b  = bh / H_;
  const int h  = bh % H_;
  const int q0 = qt * 64;
  const int tbeg = c * 8;
  const int tend = (tbeg + 7 < qt) ? tbeg + 7 : qt;

  __shared__ __align__(16) bf16 Qs[64][72];
  __shared__ __align__(16) bf16 Ks[64][72];
  __shared__ __align__(16) bf16 Vt[64][72];
  __shared__ __align__(16) bf16 Ps[4][16][72];

  const int tid = threadIdx.x, lane = tid & 63, w = tid >> 6;
  const int fr = lane & 15, quad = lane >> 4, fk = quad * 8;
  const long base = ((long)b * T_) * D_ + h * HD_;
  const long vbase = (long)bh * HD_ * T_;

  {
    const int srow = tid >> 2, scol = (tid & 3) * 16;
    const long g = base + (long)(q0 + srow) * D_ + scol;
    *(bf16x8*)&Qs[srow][scol]     = *(const bf16x8*)&q[g];
    *(bf16x8*)&Qs[srow][scol + 8] = *(const bf16x8*)&q[g + 8];
  }

  float m_st = -1e30f, l_st = 0.f;
  floatx4 o[4] = {};
  const float SC = 0.125f * LOG2E;

  for (int t = tbeg; t <= tend; t++) {
    const int k0 = t * 64;
    __syncthreads();
    {
      const int srow = tid >> 2, scol = (tid & 3) * 16;
      const long kg = base + (long)(k0 + srow) * D_ + scol;
      *(bf16x8*)&Ks[srow][scol]     = *(const bf16x8*)&k[kg];
      *(bf16x8*)&Ks[srow][scol + 8] = *(const bf16x8*)&k[kg + 8];
      const long vg = vbase + (long)srow * T_ + k0 + scol;
      *(bf16x8*)&Vt[srow][scol]     = *(const bf16x8*)&vtg[vg];
      *(bf16x8*)&Vt[srow][scol + 8] = *(const bf16x8*)&vtg[vg + 8];
    }
    __syncthreads();

    floatx4 s[4] = {};
#pragma unroll
    for (int kd = 0; kd < 2; kd++) {
      const bf16x8 bq = *(const bf16x8*)&Qs[w * 16 + fr][kd * 32 + fk];
#pragma unroll
      for (int kt = 0; kt < 4; kt++) {
        const bf16x8 ak = *(const bf16x8*)&Ks[kt * 16 + fr][kd * 32 + fk];
        s[kt] = mfma_bf16(ak, bq, s[kt]);
      }
    }

    if (t == qt) {
      const int qloc = w * 16 + fr;
#pragma unroll
      for (int kt = 0; kt < 4; kt++)
#pragma unroll
        for (int r2 = 0; r2 < 4; r2++) {
          const int kvloc = kt * 16 + quad * 4 + r2;
          s[kt][r2] = (kvloc > qloc) ? -1e30f : s[kt][r2] * SC;
        }
    } else {
#pragma unroll
      for (int kt = 0; kt < 4; kt++)
#pragma unroll
        for (int r2 = 0; r2 < 4; r2++) s[kt][r2] *= SC;
    }

    float mx = -1e30f;
#pragma unroll
    for (int kt = 0; kt < 4; kt++)
#pragma unroll
      for (int r2 = 0; r2 < 4; r2++) mx = fmaxf(mx, s[kt][r2]);
    mx = fmaxf(mx, __shfl_xor(mx, 16));
    mx = fmaxf(mx, __shfl_xor(mx, 32));
    const float mnew  = fmaxf(m_st, mx);
    const float alpha = exp2f(m_st - mnew);
    m_st = mnew;
    float rs = 0.f;
#pragma unroll
    for (int kt = 0; kt < 4; kt++)
#pragma unroll
      for (int r2 = 0; r2 < 4; r2++) {
        const float pv = exp2f(s[kt][r2] - mnew);
        s[kt][r2] = pv;
        rs += pv;
      }
    rs += __shfl_xor(rs, 16);
    rs += __shfl_xor(rs, 32);
    l_st = l_st * alpha + rs;
#pragma unroll
    for (int ht = 0; ht < 4; ht++) o[ht] *= alpha;

#pragma unroll
    for (int kt = 0; kt < 4; kt++) {
      bf16x4 pk;
#pragma unroll
      for (int r2 = 0; r2 < 4; r2++) pk[r2] = (bf16)s[kt][r2];
      *(bf16x4*)&Ps[w][fr][kt * 16 + quad * 4] = pk;
    }

#pragma unroll
    for (int kq = 0; kq < 2; kq++) {
      const bf16x8 bp = *(const bf16x8*)&Ps[w][fr][kq * 32 + fk];
#pragma unroll
      for (int ht = 0; ht < 4; ht++) {
        const bf16x8 av = *(const bf16x8*)&Vt[ht * 16 + fr][kq * 32 + fk];
        o[ht] = mfma_bf16(av, bp, o[ht]);
      }
    }
  }

  const int qq = w * 16 + fr;
  const long pg = (long)gid * 4096 + qq * 64;
#pragma unroll
  for (int ht = 0; ht < 4; ht++)
    *(floatx4*)&po[pg + ht * 16 + quad * 4] = o[ht];
  if (quad == 0) { pm[gid * 64 + qq] = m_st; pl[gid * 64 + qq] = l_st; }
}

// ---------------------------------------------------------------------------
// Combine flash split-K partials: block = (bh, qt), 768 blocks.
// ---------------------------------------------------------------------------
__global__ __launch_bounds__(256)
void flash_comb(const float* __restrict__ po, const float* __restrict__ pm,
                const float* __restrict__ pl, bf16* __restrict__ y) {
  const int bh = blockIdx.x >> 5;
  const int qt = blockIdx.x & 31;
  const int b = bh / H_, h = bh % H_;
  const int nc = (qt >> 3) + 1;
  int bse;
  if      (qt <  8) bse = qt;
  else if (qt < 16) bse = 8  + 2 * (qt - 8);
  else if (qt < 24) bse = 24 + 3 * (qt - 16);
  else              bse = 48 + 4 * (qt - 24);
  const int g0 = bh * 80 + bse;

  const int t = threadIdx.x;
  const int qq = t >> 2, hg = (t & 3) * 16;

  float M = -1e30f;
  for (int c2 = 0; c2 < nc; c2++) M = fmaxf(M, pm[(g0 + c2) * 64 + qq]);
  float l = 0.f;
  floatx4 o[4] = {};
  for (int c2 = 0; c2 < nc; c2++) {
    const float wgt = exp2f(pm[(g0 + c2) * 64 + qq] - M);
    l += wgt * pl[(g0 + c2) * 64 + qq];
    const long pg = (long)(g0 + c2) * 4096 + qq * 64 + hg;
#pragma unroll
    for (int j = 0; j < 4; j++) {
      const floatx4 t4 = *(const floatx4*)&po[pg + j * 4];
#pragma unroll
      for (int e = 0; e < 4; e++) o[j][e] += wgt * t4[e];
    }
  }
  const float inv = 1.f / l;
  bf16x8 r0, r1;
#pragma unroll
  for (int e = 0; e < 4; e++) {
    r0[e]     = (bf16)(o[0][e] * inv);
    r0[4 + e] = (bf16)(o[1][e] * inv);
    r1[e]     = (bf16)(o[2][e] * inv);
    r1[4 + e] = (bf16)(o[3][e] * inv);
  }
  const long yoff = ((long)b * T_ + qt * 64 + qq) * D_ + h * HD_ + hg;
  *(bf16x8*)&y[yoff]     = r0;
  *(bf16x8*)&y[yoff + 8] = r1;
}

// ---------------------------------------------------------------------------
extern "C" void kernel_launch(void* const* d_in, const int* in_sizes, int n_in,
                              void* d_out, int out_size, void* d_ws, size_t ws_size,
                              hipStream_t stream) {
  const float* x    = (const float*)d_in[0];
  const float* wq   = (const float*)d_in[1];
  const float* wk   = (const float*)d_in[2];
  const float* wv   = (const float*)d_in[3];
  const float* wo   = (const float*)d_in[4];
  const float* w1   = (const float*)d_in[5];
  const float* w2   = (const float*)d_in[6];
  const float* w3   = (const float*)d_in[7];
  const float* anw  = (const float*)d_in[8];
  const float* fnw  = (const float*)d_in[9];
  const float* cosb = (const float*)d_in[10];
  const float* sinb = (const float*)d_in[11];

  char* ws = (char*)d_ws;
  // Layout (bytes), total 88,080,384. Aliasing by lifetime:
  //   po/pm/pl (flash->comb) overlay xm+g region (written later).
  //   w3 partials: p30 = qb+kb (dead after flash), p31 = yb+hn (dead after w12).
  bf16*  wb  = (bf16*)(ws + 0);                // 18,874,368
  bf16*  wqb = wb;
  bf16*  wkb = wb +  589824;
  bf16*  wvb = wb + 1179648;
  bf16*  wob = wb + 1769472;
  bf16*  w1b = wb + 2359296;
  bf16*  w2b = wb + 4718592;
  bf16*  w3b = wb + 7077888;
  bf16*  qb  = (bf16*)(ws + 18874368);
  bf16*  kb  = (bf16*)(ws + 25165824);
  bf16*  vt  = (bf16*)(ws + 31457280);
  bf16*  yb  = (bf16*)(ws + 37748736);
  bf16*  hn  = (bf16*)(ws + 44040192);
  float* xm  = (float*)(ws + 50331648);        // 12,582,912
  bf16*  g   = (bf16*)(ws + 62914560);         // 25,165,824
  float* po  = (float*)(ws + 50331648);        // 31,457,280 (pre-xm/g lifetime)
  float* pm  = (float*)(ws + 81788928);
  float* pl  = (float*)(ws + 82280448);
  float* p30 = (float*)(ws + 18874368);        // 12,582,912 (over qb+kb)
  float* p31 = (float*)(ws + 37748736);        // 12,582,912 (over yb+hn)

  cvt_k<<<4608, 256, 0, stream>>>(wq, wk, wv, wo, w1, w2, w3, wb);
  rmsnorm_k<<<4096, 256, 0, stream>>>(x, anw, hn);
  gemm_qkv<<<dim3(18, 32), 256, 0, stream>>>(hn, wqb, wkb, wvb, qb, kb, vt, cosb, sinb);
  flash_attn<<<1920, 256, 0, stream>>>(qb, kb, vt, po, pm, pl);
  flash_comb<<<768, 256, 0, stream>>>(po, pm, pl, yb);
  gemm_n64<<<384, 256, 0, stream>>>(yb, wob, xm, x, 768, 768);
  rmsnorm_k<<<4096, 256, 0, stream>>>(xm, fnw, hn);
  gemm_w12<<<1536, 256, 0, stream>>>(hn, w1b, w2b, g);
  gemm_w3sk<<<768, 256, 0, stream>>>(g, w3b, p30, p31);
  comb3_k<<<1536, 256, 0, stream>>>(p30, p31, xm, (float*)d_out);
}

// Round 8
// 298.460 us; speedup vs baseline: 1.6065x; 1.0346x over previous
//
#include <hip/hip_runtime.h>
#include <hip/hip_bf16.h>
#include <math.h>

typedef __bf16 bf16;
typedef __bf16 bf16x4 __attribute__((ext_vector_type(4)));
typedef __bf16 bf16x8 __attribute__((ext_vector_type(8)));
typedef float floatx4 __attribute__((ext_vector_type(4)));

#define T_ 2048
#define D_ 768
#define H_ 12
#define HD_ 64
#define FF_ 3072
#define LOG2E 1.44269504f
#define LDP 72   // padded LDS row stride (elems)

__device__ __forceinline__ floatx4 mfma_bf16(bf16x8 a, bf16x8 b, floatx4 c) {
  return __builtin_amdgcn_mfma_f32_16x16x32_bf16(a, b, c, 0, 0, 0);
}

// ---------------------------------------------------------------------------
// Fused prologue: blocks [0,4608) convert 7 fp32 weight mats -> bf16;
// blocks [4608,8704) do attn rmsnorm (row = blk-4608).
// ---------------------------------------------------------------------------
__device__ __forceinline__ void rms_row(const float* __restrict__ x,
                                        const float* __restrict__ wt,
                                        bf16* __restrict__ o, int row, int tid) {
  const long off = (long)row * D_;
  float vals[3];
  float ss = 0.f;
#pragma unroll
  for (int i = 0; i < 3; i++) {
    vals[i] = x[off + tid + i * 256];
    ss += vals[i] * vals[i];
  }
#pragma unroll
  for (int d = 1; d < 64; d <<= 1) ss += __shfl_xor(ss, d);
  __shared__ float wsum[4];
  if ((tid & 63) == 0) wsum[tid >> 6] = ss;
  __syncthreads();
  const float tot = wsum[0] + wsum[1] + wsum[2] + wsum[3];
  const float inv = 1.0f / (sqrtf(tot * (1.0f / 768.0f)) + 1e-6f);
#pragma unroll
  for (int i = 0; i < 3; i++)
    o[off + tid + i * 256] = (bf16)(vals[i] * inv * wt[tid + i * 256]);
}

__global__ __launch_bounds__(256)
void prep_k(const float* __restrict__ wq, const float* __restrict__ wk,
            const float* __restrict__ wv, const float* __restrict__ wo,
            const float* __restrict__ w1, const float* __restrict__ w2,
            const float* __restrict__ w3, bf16* __restrict__ o,
            const float* __restrict__ x, const float* __restrict__ anw,
            bf16* __restrict__ hn) {
  if (blockIdx.x >= 4608) {
    rms_row(x, anw, hn, blockIdx.x - 4608, threadIdx.x);
    return;
  }
  const long i = ((long)blockIdx.x * 256 + threadIdx.x) * 8;
  const float* s;
  if      (i <  589824) s = wq + i;
  else if (i < 1179648) s = wk + (i -  589824);
  else if (i < 1769472) s = wv + (i - 1179648);
  else if (i < 2359296) s = wo + (i - 1769472);
  else if (i < 4718592) s = w1 + (i - 2359296);
  else if (i < 7077888) s = w2 + (i - 4718592);
  else                  s = w3 + (i - 7077888);
  const floatx4 a = *(const floatx4*)s;
  const floatx4 b = *(const floatx4*)(s + 4);
  bf16x8 r;
#pragma unroll
  for (int j = 0; j < 4; j++) { r[j] = (bf16)a[j]; r[4 + j] = (bf16)b[j]; }
  *(bf16x8*)&o[i] = r;
}

// ---------------------------------------------------------------------------
// RMSNorm standalone (ffn norm).
// ---------------------------------------------------------------------------
__global__ __launch_bounds__(256)
void rmsnorm_k(const float* __restrict__ x, const float* __restrict__ wt,
               bf16* __restrict__ o) {
  rms_row(x, wt, o, blockIdx.x, threadIdx.x);
}

// ---------------------------------------------------------------------------
// Fused QKV GEMM, 128x128 tile, BK=64, register-prefetch. Epilogue:
//   widx 0/1 (q,k): RoPE in-register (shfl_xor pair exchange).
//   widx 2   (v)  : store transposed to vt[bh][hd][t] (bf16x4).
// ---------------------------------------------------------------------------
__global__ __launch_bounds__(256)
void gemm_qkv(const bf16* __restrict__ A, const bf16* __restrict__ wq,
              const bf16* __restrict__ wk, const bf16* __restrict__ wv,
              bf16* __restrict__ q, bf16* __restrict__ k, bf16* __restrict__ vt,
              const float* __restrict__ cosb, const float* __restrict__ sinb) {
  const int widx = blockIdx.x / 6;
  const int nb   = blockIdx.x % 6;
  const bf16* W = (widx == 0) ? wq : (widx == 1) ? wk : wv;
  const int m0 = blockIdx.y * 128, n0 = nb * 128;
  const int K = D_;

  __shared__ __align__(16) bf16 As[128 * LDP];
  __shared__ __align__(16) bf16 Ws[128 * LDP];

  const int tid = threadIdx.x;
  const int lane = tid & 63;
  const int wm = tid >> 7;
  const int wn = (tid >> 6) & 1;
  const int fr = lane & 15;
  const int fk = (lane >> 4) * 8;

  floatx4 acc[4][4] = {};

  const int ar = tid >> 3;
  const int ac = (tid & 7) * 8;
  const bf16* Aptr = A + (long)(m0 + ar) * K + ac;
  const bf16* Wptr = W + (long)(n0 + ar) * K + ac;
  const long rstep = (long)32 * K;

  bf16x8 apf[4], wpf[4];
#pragma unroll
  for (int c = 0; c < 4; c++) apf[c] = *(const bf16x8*)(Aptr + c * rstep);
#pragma unroll
  for (int c = 0; c < 4; c++) wpf[c] = *(const bf16x8*)(Wptr + c * rstep);

  const int ns = K >> 6;   // 12
  for (int ks = 0; ks < ns; ks++) {
    __syncthreads();
#pragma unroll
    for (int c = 0; c < 4; c++) *(bf16x8*)&As[(ar + c * 32) * LDP + ac] = apf[c];
#pragma unroll
    for (int c = 0; c < 4; c++) *(bf16x8*)&Ws[(ar + c * 32) * LDP + ac] = wpf[c];
    __syncthreads();
    const long koff = (long)((ks + 1 < ns) ? ks + 1 : ks) * 64;
#pragma unroll
    for (int c = 0; c < 4; c++) apf[c] = *(const bf16x8*)(Aptr + koff + c * rstep);
#pragma unroll
    for (int c = 0; c < 4; c++) wpf[c] = *(const bf16x8*)(Wptr + koff + c * rstep);
#pragma unroll
    for (int kc = 0; kc < 2; kc++) {
      bf16x8 af[4], bfv[4];
#pragma unroll
      for (int i = 0; i < 4; i++) af[i]  = *(const bf16x8*)&As[(wm * 64 + i * 16 + fr) * LDP + kc * 32 + fk];
#pragma unroll
      for (int j = 0; j < 4; j++) bfv[j] = *(const bf16x8*)&Ws[(wn * 64 + j * 16 + fr) * LDP + kc * 32 + fk];
#pragma unroll
      for (int i = 0; i < 4; i++)
#pragma unroll
        for (int j = 0; j < 4; j++)
          acc[i][j] = mfma_bf16(af[i], bfv[j], acc[i][j]);
    }
  }

  const int rb = (lane >> 4) * 4;
  if (widx < 2) {
    bf16* O = (widx == 0) ? q : k;
    const float sgn = (fr & 1) ? 1.f : -1.f;
#pragma unroll
    for (int i = 0; i < 4; i++)
#pragma unroll
      for (int j = 0; j < 4; j++) {
        const int n = n0 + wn * 64 + j * 16 + fr;
        const int d = n & 63;
#pragma unroll
        for (int r = 0; r < 4; r++) {
          const int m = m0 + wm * 64 + i * 16 + rb + r;
          const int pos = m & (T_ - 1);
          const float val = acc[i][j][r];
          const float par = __shfl_xor(val, 1);
          const float cc = cosb[pos * HD_ + d];
          const float ss = sinb[pos * HD_ + d];
          O[(long)m * D_ + n] = (bf16)(val * cc + sgn * par * ss);
        }
      }
  } else {
#pragma unroll
    for (int i = 0; i < 4; i++)
#pragma unroll
      for (int j = 0; j < 4; j++) {
        const int n = n0 + wn * 64 + j * 16 + fr;
        const int m = m0 + wm * 64 + i * 16 + rb;
        const int b = m >> 11;
        const int t = m & (T_ - 1);
        const long row = (long)(b * H_ + (n >> 6)) * HD_ + (n & 63);
        bf16x4 pk;
#pragma unroll
        for (int r = 0; r < 4; r++) pk[r] = (bf16)acc[i][j][r];
        *(bf16x4*)&vt[row * T_ + t] = pk;
      }
  }
}

// ---------------------------------------------------------------------------
// GEMM 128x64 tile for wo (N=768, K=768). 384 blocks, XCD-swizzled.
// Epilogue: f32 C = acc + f32 resid.
// ---------------------------------------------------------------------------
__global__ __launch_bounds__(256)
void gemm_n64(const bf16* __restrict__ A, const bf16* __restrict__ W,
              float* __restrict__ C, const float* __restrict__ resid,
              int N, int K) {
  __shared__ __align__(16) bf16 As[128 * LDP];
  __shared__ __align__(16) bf16 Ws[64 * LDP];

  const int L  = blockIdx.x;
  const int j  = L >> 3;
  const int mb = (L & 7) * 4 + (j / 12);
  const int nb = j % 12;
  const int m0 = mb * 128, n0 = nb * 64;

  const int tid = threadIdx.x;
  const int lane = tid & 63;
  const int wm = tid >> 7;
  const int wn = (tid >> 6) & 1;
  const int fr = lane & 15;
  const int fk = (lane >> 4) * 8;

  floatx4 acc[4][2] = {};

  const int ar = tid >> 3;
  const int ac = (tid & 7) * 8;
  const bf16* Aptr = A + (long)(m0 + ar) * K + ac;
  const bf16* Wptr = W + (long)(n0 + ar) * K + ac;
  const long rstep = (long)32 * K;

  bf16x8 apf[4], wpf[2];
#pragma unroll
  for (int c = 0; c < 4; c++) apf[c] = *(const bf16x8*)(Aptr + c * rstep);
#pragma unroll
  for (int c = 0; c < 2; c++) wpf[c] = *(const bf16x8*)(Wptr + c * rstep);

  const int ns = K >> 6;
  for (int ks = 0; ks < ns; ks++) {
    __syncthreads();
#pragma unroll
    for (int c = 0; c < 4; c++) *(bf16x8*)&As[(ar + c * 32) * LDP + ac] = apf[c];
#pragma unroll
    for (int c = 0; c < 2; c++) *(bf16x8*)&Ws[(ar + c * 32) * LDP + ac] = wpf[c];
    __syncthreads();
    const long koff = (long)((ks + 1 < ns) ? ks + 1 : ks) * 64;
#pragma unroll
    for (int c = 0; c < 4; c++) apf[c] = *(const bf16x8*)(Aptr + koff + c * rstep);
#pragma unroll
    for (int c = 0; c < 2; c++) wpf[c] = *(const bf16x8*)(Wptr + koff + c * rstep);
#pragma unroll
    for (int kc = 0; kc < 2; kc++) {
      bf16x8 af[4], bfv[2];
#pragma unroll
      for (int i = 0; i < 4; i++) af[i]  = *(const bf16x8*)&As[(wm * 64 + i * 16 + fr) * LDP + kc * 32 + fk];
#pragma unroll
      for (int j2 = 0; j2 < 2; j2++) bfv[j2] = *(const bf16x8*)&Ws[(wn * 32 + j2 * 16 + fr) * LDP + kc * 32 + fk];
#pragma unroll
      for (int i = 0; i < 4; i++)
#pragma unroll
        for (int j2 = 0; j2 < 2; j2++)
          acc[i][j2] = mfma_bf16(af[i], bfv[j2], acc[i][j2]);
    }
  }

  const int rb = (lane >> 4) * 4;
#pragma unroll
  for (int i = 0; i < 4; i++)
#pragma unroll
    for (int j2 = 0; j2 < 2; j2++) {
      const int n = n0 + wn * 32 + j2 * 16 + fr;
#pragma unroll
      for (int r = 0; r < 4; r++) {
        const int m = m0 + wm * 64 + i * 16 + rb + r;
        const long idx = (long)m * N + n;
        C[idx] = acc[i][j2][r] + resid[idx];
      }
    }
}

// ---------------------------------------------------------------------------
// w3 GEMM, split-K x2: 768 blocks, each K-half of 1536 (24 steps).
// ---------------------------------------------------------------------------
__global__ __launch_bounds__(256)
void gemm_w3sk(const bf16* __restrict__ A, const bf16* __restrict__ W,
               float* __restrict__ p0, float* __restrict__ p1) {
  __shared__ __align__(16) bf16 As[128 * LDP];
  __shared__ __align__(16) bf16 Ws[64 * LDP];

  const int L  = blockIdx.x;
  const int j  = L >> 3;                  // 0..95
  const int mb = (L & 7) * 4 + (j / 24);
  const int inner = j % 24;
  const int s  = inner / 12;
  const int nb = inner % 12;
  const int m0 = mb * 128, n0 = nb * 64;
  const int K = FF_;
  const int kbase = s * 1536;
  float* C = s ? p1 : p0;

  const int tid = threadIdx.x;
  const int lane = tid & 63;
  const int wm = tid >> 7;
  const int wn = (tid >> 6) & 1;
  const int fr = lane & 15;
  const int fk = (lane >> 4) * 8;

  floatx4 acc[4][2] = {};

  const int ar = tid >> 3;
  const int ac = (tid & 7) * 8;
  const bf16* Aptr = A + (long)(m0 + ar) * K + kbase + ac;
  const bf16* Wptr = W + (long)(n0 + ar) * K + kbase + ac;
  const long rstep = (long)32 * K;

  bf16x8 apf[4], wpf[2];
#pragma unroll
  for (int c = 0; c < 4; c++) apf[c] = *(const bf16x8*)(Aptr + c * rstep);
#pragma unroll
  for (int c = 0; c < 2; c++) wpf[c] = *(const bf16x8*)(Wptr + c * rstep);

  const int ns = 24;
  for (int ks = 0; ks < ns; ks++) {
    __syncthreads();
#pragma unroll
    for (int c = 0; c < 4; c++) *(bf16x8*)&As[(ar + c * 32) * LDP + ac] = apf[c];
#pragma unroll
    for (int c = 0; c < 2; c++) *(bf16x8*)&Ws[(ar + c * 32) * LDP + ac] = wpf[c];
    __syncthreads();
    const long koff = (long)((ks + 1 < ns) ? ks + 1 : ks) * 64;
#pragma unroll
    for (int c = 0; c < 4; c++) apf[c] = *(const bf16x8*)(Aptr + koff + c * rstep);
#pragma unroll
    for (int c = 0; c < 2; c++) wpf[c] = *(const bf16x8*)(Wptr + koff + c * rstep);
#pragma unroll
    for (int kc = 0; kc < 2; kc++) {
      bf16x8 af[4], bfv[2];
#pragma unroll
      for (int i = 0; i < 4; i++) af[i]  = *(const bf16x8*)&As[(wm * 64 + i * 16 + fr) * LDP + kc * 32 + fk];
#pragma unroll
      for (int j2 = 0; j2 < 2; j2++) bfv[j2] = *(const bf16x8*)&Ws[(wn * 32 + j2 * 16 + fr) * LDP + kc * 32 + fk];
#pragma unroll
      for (int i = 0; i < 4; i++)
#pragma unroll
        for (int j2 = 0; j2 < 2; j2++)
          acc[i][j2] = mfma_bf16(af[i], bfv[j2], acc[i][j2]);
    }
  }

  const int rb = (lane >> 4) * 4;
#pragma unroll
  for (int i = 0; i < 4; i++)
#pragma unroll
    for (int j2 = 0; j2 < 2; j2++) {
      const int n = n0 + wn * 32 + j2 * 16 + fr;
#pragma unroll
      for (int r = 0; r < 4; r++) {
        const int m = m0 + wm * 64 + i * 16 + rb + r;
        C[(long)m * D_ + n] = acc[i][j2][r];
      }
    }
}

// out = p0 + p1 + xm (fp32), 3.1M elems, 8/thread.
__global__ __launch_bounds__(256)
void comb3_k(const float* __restrict__ p0, const float* __restrict__ p1,
             const float* __restrict__ xm, float* __restrict__ out) {
  const long i = ((long)blockIdx.x * 256 + threadIdx.x) * 8;
#pragma unroll
  for (int c = 0; c < 2; c++) {
    const floatx4 a = *(const floatx4*)&p0[i + c * 4];
    const floatx4 b = *(const floatx4*)&p1[i + c * 4];
    const floatx4 d = *(const floatx4*)&xm[i + c * 4];
    floatx4 r;
#pragma unroll
    for (int e = 0; e < 4; e++) r[e] = a[e] + b[e] + d[e];
    *(floatx4*)&out[i + c * 4] = r;
  }
}

// ---------------------------------------------------------------------------
// Fused w1/w2 GEMM + silu-mul. 128x128 DUAL tile: acc1 (W1) + acc2 (W2) over
// full n-width 128. 768 blocks (32 mb x 24 nb), 3/XCD n-stripes, mb outer.
// LDS 55.3 KB -> 2 blocks/CU. acc1/acc2 phases sequenced to limit live frags.
// ---------------------------------------------------------------------------
__global__ __launch_bounds__(256, 2)
void gemm_w12(const bf16* __restrict__ A, const bf16* __restrict__ W1,
              const bf16* __restrict__ W2, bf16* __restrict__ G) {
  __shared__ __align__(16) bf16 As[128 * LDP];
  __shared__ __align__(16) bf16 W1s[128 * LDP];
  __shared__ __align__(16) bf16 W2s[128 * LDP];

  const int L  = blockIdx.x;
  const int j  = L >> 3;                  // 0..95
  const int mb = j / 3;                   // 0..31 (outer per XCD)
  const int nb = (L & 7) * 3 + (j % 3);   // 0..23
  const int m0 = mb * 128, n0 = nb * 128;
  const int K = D_;

  const int tid = threadIdx.x;
  const int lane = tid & 63;
  const int wm = tid >> 7;
  const int wn = (tid >> 6) & 1;
  const int fr = lane & 15;
  const int fk = (lane >> 4) * 8;

  floatx4 acc1[4][4] = {}, acc2[4][4] = {};

  const int ar = tid >> 3;
  const int ac = (tid & 7) * 8;
  const bf16* Aptr  = A  + (long)(m0 + ar) * K + ac;
  const bf16* W1ptr = W1 + (long)(n0 + ar) * K + ac;
  const bf16* W2ptr = W2 + (long)(n0 + ar) * K + ac;
  const long rstep = (long)32 * K;

  bf16x8 apf[4], w1pf[4], w2pf[4];
#pragma unroll
  for (int c = 0; c < 4; c++) { apf[c]  = *(const bf16x8*)(Aptr  + c * rstep);
                                w1pf[c] = *(const bf16x8*)(W1ptr + c * rstep);
                                w2pf[c] = *(const bf16x8*)(W2ptr + c * rstep); }

  const int ns = K >> 6;   // 12
  for (int ks = 0; ks < ns; ks++) {
    __syncthreads();
#pragma unroll
    for (int c = 0; c < 4; c++) { *(bf16x8*)&As[(ar + c * 32) * LDP + ac]  = apf[c];
                                  *(bf16x8*)&W1s[(ar + c * 32) * LDP + ac] = w1pf[c];
                                  *(bf16x8*)&W2s[(ar + c * 32) * LDP + ac] = w2pf[c]; }
    __syncthreads();
    const long koff = (long)((ks + 1 < ns) ? ks + 1 : ks) * 64;
#pragma unroll
    for (int c = 0; c < 4; c++) { apf[c]  = *(const bf16x8*)(Aptr  + koff + c * rstep);
                                  w1pf[c] = *(const bf16x8*)(W1ptr + koff + c * rstep);
                                  w2pf[c] = *(const bf16x8*)(W2ptr + koff + c * rstep); }
#pragma unroll
    for (int kc = 0; kc < 2; kc++) {
      bf16x8 af[4];
#pragma unroll
      for (int i = 0; i < 4; i++) af[i] = *(const bf16x8*)&As[(wm * 64 + i * 16 + fr) * LDP + kc * 32 + fk];
      {
        bf16x8 b1[4];
#pragma unroll
        for (int jj = 0; jj < 4; jj++) b1[jj] = *(const bf16x8*)&W1s[(wn * 64 + jj * 16 + fr) * LDP + kc * 32 + fk];
#pragma unroll
        for (int i = 0; i < 4; i++)
#pragma unroll
          for (int jj = 0; jj < 4; jj++)
            acc1[i][jj] = mfma_bf16(af[i], b1[jj], acc1[i][jj]);
      }
      {
        bf16x8 b2[4];
#pragma unroll
        for (int jj = 0; jj < 4; jj++) b2[jj] = *(const bf16x8*)&W2s[(wn * 64 + jj * 16 + fr) * LDP + kc * 32 + fk];
#pragma unroll
        for (int i = 0; i < 4; i++)
#pragma unroll
          for (int jj = 0; jj < 4; jj++)
            acc2[i][jj] = mfma_bf16(af[i], b2[jj], acc2[i][jj]);
      }
    }
  }

  const int rb = (lane >> 4) * 4;
#pragma unroll
  for (int i = 0; i < 4; i++)
#pragma unroll
    for (int jj = 0; jj < 4; jj++) {
      const int n = n0 + wn * 64 + jj * 16 + fr;
#pragma unroll
      for (int r = 0; r < 4; r++) {
        const int m = m0 + wm * 64 + i * 16 + rb + r;
        const float a1 = acc1[i][jj][r];
        const float a2 = acc2[i][jj][r];
        const float s = a1 / (1.f + exp2f(-a1 * LOG2E));
        G[(long)m * FF_ + n] = (bf16)(s * a2);
      }
    }
}

// ---------------------------------------------------------------------------
// Flash attention, split-K over KV. Block = (bh, qt, chunk), <=8 rounds.
// ---------------------------------------------------------------------------
__global__ __launch_bounds__(256, 4)
void flash_attn(const bf16* __restrict__ q, const bf16* __restrict__ k,
                const bf16* __restrict__ vtg, float* __restrict__ po,
                float* __restrict__ pm, float* __restrict__ pl) {
  const int gid = blockIdx.x;
  const int bh = gid / 80;
  const int r  = gid % 80;
  int qt, c;
  if (r < 8)       { qt = r; c = 0; }
  else if (r < 24) { qt = 8 + ((r - 8) >> 1); c = (r - 8) & 1; }
  else if (r < 48) { const int u = r - 24; const int d = u / 3; qt = 16 + d; c = u - d * 3; }
  else             { const int u = r - 48; qt = 24 + (u >> 2); c = u & 3; }
  const int b  = bh / H_;
  const int h  = bh % H_;
  const int q0 = qt * 64;
  const int tbeg = c * 8;
  const int tend = (tbeg + 7 < qt) ? tbeg + 7 : qt;

  __shared__ __align__(16) bf16 Qs[64][72];
  __shared__ __align__(16) bf16 Ks[64][72];
  __shared__ __align__(16) bf16 Vt[64][72];
  __shared__ __align__(16) bf16 Ps[4][16][72];

  const int tid = threadIdx.x, lane = tid & 63, w = tid >> 6;
  const int fr = lane & 15, quad = lane >> 4, fk = quad * 8;
  const long base = ((long)b * T_) * D_ + h * HD_;
  const long vbase = (long)bh * HD_ * T_;

  {
    const int srow = tid >> 2, scol = (tid & 3) * 16;
    const long g = base + (long)(q0 + srow) * D_ + scol;
    *(bf16x8*)&Qs[srow][scol]     = *(const bf16x8*)&q[g];
    *(bf16x8*)&Qs[srow][scol + 8] = *(const bf16x8*)&q[g + 8];
  }

  float m_st = -1e30f, l_st = 0.f;
  floatx4 o[4] = {};
  const float SC = 0.125f * LOG2E;

  for (int t = tbeg; t <= tend; t++) {
    const int k0 = t * 64;
    __syncthreads();
    {
      const int srow = tid >> 2, scol = (tid & 3) * 16;
      const long kg = base + (long)(k0 + srow) * D_ + scol;
      *(bf16x8*)&Ks[srow][scol]     = *(const bf16x8*)&k[kg];
      *(bf16x8*)&Ks[srow][scol + 8] = *(const bf16x8*)&k[kg + 8];
      const long vg = vbase + (long)srow * T_ + k0 + scol;
      *(bf16x8*)&Vt[srow][scol]     = *(const bf16x8*)&vtg[vg];
      *(bf16x8*)&Vt[srow][scol + 8] = *(const bf16x8*)&vtg[vg + 8];
    }
    __syncthreads();

    floatx4 s[4] = {};
#pragma unroll
    for (int kd = 0; kd < 2; kd++) {
      const bf16x8 bq = *(const bf16x8*)&Qs[w * 16 + fr][kd * 32 + fk];
#pragma unroll
      for (int kt = 0; kt < 4; kt++) {
        const bf16x8 ak = *(const bf16x8*)&Ks[kt * 16 + fr][kd * 32 + fk];
        s[kt] = mfma_bf16(ak, bq, s[kt]);
      }
    }

    if (t == qt) {
      const int qloc = w * 16 + fr;
#pragma unroll
      for (int kt = 0; kt < 4; kt++)
#pragma unroll
        for (int r2 = 0; r2 < 4; r2++) {
          const int kvloc = kt * 16 + quad * 4 + r2;
          s[kt][r2] = (kvloc > qloc) ? -1e30f : s[kt][r2] * SC;
        }
    } else {
#pragma unroll
      for (int kt = 0; kt < 4; kt++)
#pragma unroll
        for (int r2 = 0; r2 < 4; r2++) s[kt][r2] *= SC;
    }

    float mx = -1e30f;
#pragma unroll
    for (int kt = 0; kt < 4; kt++)
#pragma unroll
      for (int r2 = 0; r2 < 4; r2++) mx = fmaxf(mx, s[kt][r2]);
    mx = fmaxf(mx, __shfl_xor(mx, 16));
    mx = fmaxf(mx, __shfl_xor(mx, 32));
    const float mnew  = fmaxf(m_st, mx);
    const float alpha = exp2f(m_st - mnew);
    m_st = mnew;
    float rs = 0.f;
#pragma unroll
    for (int kt = 0; kt < 4; kt++)
#pragma unroll
      for (int r2 = 0; r2 < 4; r2++) {
        const float pv = exp2f(s[kt][r2] - mnew);
        s[kt][r2] = pv;
        rs += pv;
      }
    rs += __shfl_xor(rs, 16);
    rs += __shfl_xor(rs, 32);
    l_st = l_st * alpha + rs;
#pragma unroll
    for (int ht = 0; ht < 4; ht++) o[ht] *= alpha;

#pragma unroll
    for (int kt = 0; kt < 4; kt++) {
      bf16x4 pk;
#pragma unroll
      for (int r2 = 0; r2 < 4; r2++) pk[r2] = (bf16)s[kt][r2];
      *(bf16x4*)&Ps[w][fr][kt * 16 + quad * 4] = pk;
    }

#pragma unroll
    for (int kq = 0; kq < 2; kq++) {
      const bf16x8 bp = *(const bf16x8*)&Ps[w][fr][kq * 32 + fk];
#pragma unroll
      for (int ht = 0; ht < 4; ht++) {
        const bf16x8 av = *(const bf16x8*)&Vt[ht * 16 + fr][kq * 32 + fk];
        o[ht] = mfma_bf16(av, bp, o[ht]);
      }
    }
  }

  const int qq = w * 16 + fr;
  const long pg = (long)gid * 4096 + qq * 64;
#pragma unroll
  for (int ht = 0; ht < 4; ht++)
    *(floatx4*)&po[pg + ht * 16 + quad * 4] = o[ht];
  if (quad == 0) { pm[gid * 64 + qq] = m_st; pl[gid * 64 + qq] = l_st; }
}

// ---------------------------------------------------------------------------
// Combine flash split-K partials: block = (bh, qt), 768 blocks.
// ---------------------------------------------------------------------------
__global__ __launch_bounds__(256)
void flash_comb(const float* __restrict__ po, const float* __restrict__ pm,
                const float* __restrict__ pl, bf16* __restrict__ y) {
  const int bh = blockIdx.x >> 5;
  const int qt = blockIdx.x & 31;
  const int b = bh / H_, h = bh % H_;
  const int nc = (qt >> 3) + 1;
  int bse;
  if      (qt <  8) bse = qt;
  else if (qt < 16) bse = 8  + 2 * (qt - 8);
  else if (qt < 24) bse = 24 + 3 * (qt - 16);
  else              bse = 48 + 4 * (qt - 24);
  const int g0 = bh * 80 + bse;

  const int t = threadIdx.x;
  const int qq = t >> 2, hg = (t & 3) * 16;

  float M = -1e30f;
  for (int c2 = 0; c2 < nc; c2++) M = fmaxf(M, pm[(g0 + c2) * 64 + qq]);
  float l = 0.f;
  floatx4 o[4] = {};
  for (int c2 = 0; c2 < nc; c2++) {
    const float wgt = exp2f(pm[(g0 + c2) * 64 + qq] - M);
    l += wgt * pl[(g0 + c2) * 64 + qq];
    const long pg = (long)(g0 + c2) * 4096 + qq * 64 + hg;
#pragma unroll
    for (int j = 0; j < 4; j++) {
      const floatx4 t4 = *(const floatx4*)&po[pg + j * 4];
#pragma unroll
      for (int e = 0; e < 4; e++) o[j][e] += wgt * t4[e];
    }
  }
  const float inv = 1.f / l;
  bf16x8 r0, r1;
#pragma unroll
  for (int e = 0; e < 4; e++) {
    r0[e]     = (bf16)(o[0][e] * inv);
    r0[4 + e] = (bf16)(o[1][e] * inv);
    r1[e]     = (bf16)(o[2][e] * inv);
    r1[4 + e] = (bf16)(o[3][e] * inv);
  }
  const long yoff = ((long)b * T_ + qt * 64 + qq) * D_ + h * HD_ + hg;
  *(bf16x8*)&y[yoff]     = r0;
  *(bf16x8*)&y[yoff + 8] = r1;
}

// ---------------------------------------------------------------------------
extern "C" void kernel_launch(void* const* d_in, const int* in_sizes, int n_in,
                              void* d_out, int out_size, void* d_ws, size_t ws_size,
                              hipStream_t stream) {
  const float* x    = (const float*)d_in[0];
  const float* wq   = (const float*)d_in[1];
  const float* wk   = (const float*)d_in[2];
  const float* wv   = (const float*)d_in[3];
  const float* wo   = (const float*)d_in[4];
  const float* w1   = (const float*)d_in[5];
  const float* w2   = (const float*)d_in[6];
  const float* w3   = (const float*)d_in[7];
  const float* anw  = (const float*)d_in[8];
  const float* fnw  = (const float*)d_in[9];
  const float* cosb = (const float*)d_in[10];
  const float* sinb = (const float*)d_in[11];

  char* ws = (char*)d_ws;
  // Layout (bytes), total 88,080,384. Aliasing by lifetime:
  //   po/pm/pl (flash->comb) overlay xm+g region (written later).
  //   w3 partials: p30 over qb+kb (dead after flash), p31 over yb+hn.
  bf16*  wb  = (bf16*)(ws + 0);                // 18,874,368
  bf16*  wqb = wb;
  bf16*  wkb = wb +  589824;
  bf16*  wvb = wb + 1179648;
  bf16*  wob = wb + 1769472;
  bf16*  w1b = wb + 2359296;
  bf16*  w2b = wb + 4718592;
  bf16*  w3b = wb + 7077888;
  bf16*  qb  = (bf16*)(ws + 18874368);
  bf16*  kb  = (bf16*)(ws + 25165824);
  bf16*  vt  = (bf16*)(ws + 31457280);
  bf16*  yb  = (bf16*)(ws + 37748736);
  bf16*  hn  = (bf16*)(ws + 44040192);
  float* xm  = (float*)(ws + 50331648);        // 12,582,912
  bf16*  g   = (bf16*)(ws + 62914560);         // 25,165,824
  float* po  = (float*)(ws + 50331648);        // 31,457,280 (pre-xm/g lifetime)
  float* pm  = (float*)(ws + 81788928);
  float* pl  = (float*)(ws + 82280448);
  float* p30 = (float*)(ws + 18874368);        // over qb+kb
  float* p31 = (float*)(ws + 37748736);        // over yb+hn

  prep_k<<<8704, 256, 0, stream>>>(wq, wk, wv, wo, w1, w2, w3, wb, x, anw, hn);
  gemm_qkv<<<dim3(18, 32), 256, 0, stream>>>(hn, wqb, wkb, wvb, qb, kb, vt, cosb, sinb);
  flash_attn<<<1920, 256, 0, stream>>>(qb, kb, vt, po, pm, pl);
  flash_comb<<<768, 256, 0, stream>>>(po, pm, pl, yb);
  gemm_n64<<<384, 256, 0, stream>>>(yb, wob, xm, x, 768, 768);
  rmsnorm_k<<<4096, 256, 0, stream>>>(xm, fnw, hn);
  gemm_w12<<<768, 256, 0, stream>>>(hn, w1b, w2b, g);
  gemm_w3sk<<<768, 256, 0, stream>>>(g, w3b, p30, p31);
  comb3_k<<<1536, 256, 0, stream>>>(p30, p31, xm, (float*)d_out);
}

// Round 9
// 292.185 us; speedup vs baseline: 1.6410x; 1.0215x over previous
//
#include <hip/hip_runtime.h>
#include <hip/hip_bf16.h>
#include <math.h>

typedef __bf16 bf16;
typedef __bf16 bf16x4 __attribute__((ext_vector_type(4)));
typedef __bf16 bf16x8 __attribute__((ext_vector_type(8)));
typedef float floatx4 __attribute__((ext_vector_type(4)));

#define T_ 2048
#define D_ 768
#define H_ 12
#define HD_ 64
#define FF_ 3072
#define LOG2E 1.44269504f
#define LDP 72   // padded LDS row stride (elems)

__device__ __forceinline__ floatx4 mfma_bf16(bf16x8 a, bf16x8 b, floatx4 c) {
  return __builtin_amdgcn_mfma_f32_16x16x32_bf16(a, b, c, 0, 0, 0);
}

// ---------------------------------------------------------------------------
// Fused prologue: blocks [0,4608) convert 7 fp32 weight mats -> bf16;
// blocks [4608,8704) do attn rmsnorm (row = blk-4608).
// ---------------------------------------------------------------------------
__device__ __forceinline__ void rms_row(const float* __restrict__ x,
                                        const float* __restrict__ wt,
                                        bf16* __restrict__ o, int row, int tid) {
  const long off = (long)row * D_;
  float vals[3];
  float ss = 0.f;
#pragma unroll
  for (int i = 0; i < 3; i++) {
    vals[i] = x[off + tid + i * 256];
    ss += vals[i] * vals[i];
  }
#pragma unroll
  for (int d = 1; d < 64; d <<= 1) ss += __shfl_xor(ss, d);
  __shared__ float wsum[4];
  if ((tid & 63) == 0) wsum[tid >> 6] = ss;
  __syncthreads();
  const float tot = wsum[0] + wsum[1] + wsum[2] + wsum[3];
  const float inv = 1.0f / (sqrtf(tot * (1.0f / 768.0f)) + 1e-6f);
#pragma unroll
  for (int i = 0; i < 3; i++)
    o[off + tid + i * 256] = (bf16)(vals[i] * inv * wt[tid + i * 256]);
}

__global__ __launch_bounds__(256)
void prep_k(const float* __restrict__ wq, const float* __restrict__ wk,
            const float* __restrict__ wv, const float* __restrict__ wo,
            const float* __restrict__ w1, const float* __restrict__ w2,
            const float* __restrict__ w3, bf16* __restrict__ o,
            const float* __restrict__ x, const float* __restrict__ anw,
            bf16* __restrict__ hn) {
  if (blockIdx.x >= 4608) {
    rms_row(x, anw, hn, blockIdx.x - 4608, threadIdx.x);
    return;
  }
  const long i = ((long)blockIdx.x * 256 + threadIdx.x) * 8;
  const float* s;
  if      (i <  589824) s = wq + i;
  else if (i < 1179648) s = wk + (i -  589824);
  else if (i < 1769472) s = wv + (i - 1179648);
  else if (i < 2359296) s = wo + (i - 1769472);
  else if (i < 4718592) s = w1 + (i - 2359296);
  else if (i < 7077888) s = w2 + (i - 4718592);
  else                  s = w3 + (i - 7077888);
  const floatx4 a = *(const floatx4*)s;
  const floatx4 b = *(const floatx4*)(s + 4);
  bf16x8 r;
#pragma unroll
  for (int j = 0; j < 4; j++) { r[j] = (bf16)a[j]; r[4 + j] = (bf16)b[j]; }
  *(bf16x8*)&o[i] = r;
}

// ---------------------------------------------------------------------------
// RMSNorm standalone (ffn norm).
// ---------------------------------------------------------------------------
__global__ __launch_bounds__(256)
void rmsnorm_k(const float* __restrict__ x, const float* __restrict__ wt,
               bf16* __restrict__ o) {
  rms_row(x, wt, o, blockIdx.x, threadIdx.x);
}

// ---------------------------------------------------------------------------
// Fused QKV GEMM, 128x128 tile, BK=64, register-prefetch. Epilogue:
//   widx 0/1 (q,k): RoPE in-register (shfl_xor pair exchange).
//   widx 2   (v)  : store transposed to vt[bh][hd][t] (bf16x4).
// ---------------------------------------------------------------------------
__global__ __launch_bounds__(256)
void gemm_qkv(const bf16* __restrict__ A, const bf16* __restrict__ wq,
              const bf16* __restrict__ wk, const bf16* __restrict__ wv,
              bf16* __restrict__ q, bf16* __restrict__ k, bf16* __restrict__ vt,
              const float* __restrict__ cosb, const float* __restrict__ sinb) {
  const int widx = blockIdx.x / 6;
  const int nb   = blockIdx.x % 6;
  const bf16* W = (widx == 0) ? wq : (widx == 1) ? wk : wv;
  const int m0 = blockIdx.y * 128, n0 = nb * 128;
  const int K = D_;

  __shared__ __align__(16) bf16 As[128 * LDP];
  __shared__ __align__(16) bf16 Ws[128 * LDP];

  const int tid = threadIdx.x;
  const int lane = tid & 63;
  const int wm = tid >> 7;
  const int wn = (tid >> 6) & 1;
  const int fr = lane & 15;
  const int fk = (lane >> 4) * 8;

  floatx4 acc[4][4] = {};

  const int ar = tid >> 3;
  const int ac = (tid & 7) * 8;
  const bf16* Aptr = A + (long)(m0 + ar) * K + ac;
  const bf16* Wptr = W + (long)(n0 + ar) * K + ac;
  const long rstep = (long)32 * K;

  bf16x8 apf[4], wpf[4];
#pragma unroll
  for (int c = 0; c < 4; c++) apf[c] = *(const bf16x8*)(Aptr + c * rstep);
#pragma unroll
  for (int c = 0; c < 4; c++) wpf[c] = *(const bf16x8*)(Wptr + c * rstep);

  const int ns = K >> 6;   // 12
  for (int ks = 0; ks < ns; ks++) {
    __syncthreads();
#pragma unroll
    for (int c = 0; c < 4; c++) *(bf16x8*)&As[(ar + c * 32) * LDP + ac] = apf[c];
#pragma unroll
    for (int c = 0; c < 4; c++) *(bf16x8*)&Ws[(ar + c * 32) * LDP + ac] = wpf[c];
    __syncthreads();
    const long koff = (long)((ks + 1 < ns) ? ks + 1 : ks) * 64;
#pragma unroll
    for (int c = 0; c < 4; c++) apf[c] = *(const bf16x8*)(Aptr + koff + c * rstep);
#pragma unroll
    for (int c = 0; c < 4; c++) wpf[c] = *(const bf16x8*)(Wptr + koff + c * rstep);
#pragma unroll
    for (int kc = 0; kc < 2; kc++) {
      bf16x8 af[4], bfv[4];
#pragma unroll
      for (int i = 0; i < 4; i++) af[i]  = *(const bf16x8*)&As[(wm * 64 + i * 16 + fr) * LDP + kc * 32 + fk];
#pragma unroll
      for (int j = 0; j < 4; j++) bfv[j] = *(const bf16x8*)&Ws[(wn * 64 + j * 16 + fr) * LDP + kc * 32 + fk];
#pragma unroll
      for (int i = 0; i < 4; i++)
#pragma unroll
        for (int j = 0; j < 4; j++)
          acc[i][j] = mfma_bf16(af[i], bfv[j], acc[i][j]);
    }
  }

  const int rb = (lane >> 4) * 4;
  if (widx < 2) {
    bf16* O = (widx == 0) ? q : k;
    const float sgn = (fr & 1) ? 1.f : -1.f;
#pragma unroll
    for (int i = 0; i < 4; i++)
#pragma unroll
      for (int j = 0; j < 4; j++) {
        const int n = n0 + wn * 64 + j * 16 + fr;
        const int d = n & 63;
#pragma unroll
        for (int r = 0; r < 4; r++) {
          const int m = m0 + wm * 64 + i * 16 + rb + r;
          const int pos = m & (T_ - 1);
          const float val = acc[i][j][r];
          const float par = __shfl_xor(val, 1);
          const float cc = cosb[pos * HD_ + d];
          const float ss = sinb[pos * HD_ + d];
          O[(long)m * D_ + n] = (bf16)(val * cc + sgn * par * ss);
        }
      }
  } else {
#pragma unroll
    for (int i = 0; i < 4; i++)
#pragma unroll
      for (int j = 0; j < 4; j++) {
        const int n = n0 + wn * 64 + j * 16 + fr;
        const int m = m0 + wm * 64 + i * 16 + rb;
        const int b = m >> 11;
        const int t = m & (T_ - 1);
        const long row = (long)(b * H_ + (n >> 6)) * HD_ + (n & 63);
        bf16x4 pk;
#pragma unroll
        for (int r = 0; r < 4; r++) pk[r] = (bf16)acc[i][j][r];
        *(bf16x4*)&vt[row * T_ + t] = pk;
      }
  }
}

// ---------------------------------------------------------------------------
// GEMM 128x64 tile for wo (N=768, K=768). 384 blocks, XCD-swizzled.
// Epilogue: f32 C = acc + f32 resid.
// ---------------------------------------------------------------------------
__global__ __launch_bounds__(256)
void gemm_n64(const bf16* __restrict__ A, const bf16* __restrict__ W,
              float* __restrict__ C, const float* __restrict__ resid,
              int N, int K) {
  __shared__ __align__(16) bf16 As[128 * LDP];
  __shared__ __align__(16) bf16 Ws[64 * LDP];

  const int L  = blockIdx.x;
  const int j  = L >> 3;
  const int mb = (L & 7) * 4 + (j / 12);
  const int nb = j % 12;
  const int m0 = mb * 128, n0 = nb * 64;

  const int tid = threadIdx.x;
  const int lane = tid & 63;
  const int wm = tid >> 7;
  const int wn = (tid >> 6) & 1;
  const int fr = lane & 15;
  const int fk = (lane >> 4) * 8;

  floatx4 acc[4][2] = {};

  const int ar = tid >> 3;
  const int ac = (tid & 7) * 8;
  const bf16* Aptr = A + (long)(m0 + ar) * K + ac;
  const bf16* Wptr = W + (long)(n0 + ar) * K + ac;
  const long rstep = (long)32 * K;

  bf16x8 apf[4], wpf[2];
#pragma unroll
  for (int c = 0; c < 4; c++) apf[c] = *(const bf16x8*)(Aptr + c * rstep);
#pragma unroll
  for (int c = 0; c < 2; c++) wpf[c] = *(const bf16x8*)(Wptr + c * rstep);

  const int ns = K >> 6;
  for (int ks = 0; ks < ns; ks++) {
    __syncthreads();
#pragma unroll
    for (int c = 0; c < 4; c++) *(bf16x8*)&As[(ar + c * 32) * LDP + ac] = apf[c];
#pragma unroll
    for (int c = 0; c < 2; c++) *(bf16x8*)&Ws[(ar + c * 32) * LDP + ac] = wpf[c];
    __syncthreads();
    const long koff = (long)((ks + 1 < ns) ? ks + 1 : ks) * 64;
#pragma unroll
    for (int c = 0; c < 4; c++) apf[c] = *(const bf16x8*)(Aptr + koff + c * rstep);
#pragma unroll
    for (int c = 0; c < 2; c++) wpf[c] = *(const bf16x8*)(Wptr + koff + c * rstep);
#pragma unroll
    for (int kc = 0; kc < 2; kc++) {
      bf16x8 af[4], bfv[2];
#pragma unroll
      for (int i = 0; i < 4; i++) af[i]  = *(const bf16x8*)&As[(wm * 64 + i * 16 + fr) * LDP + kc * 32 + fk];
#pragma unroll
      for (int j2 = 0; j2 < 2; j2++) bfv[j2] = *(const bf16x8*)&Ws[(wn * 32 + j2 * 16 + fr) * LDP + kc * 32 + fk];
#pragma unroll
      for (int i = 0; i < 4; i++)
#pragma unroll
        for (int j2 = 0; j2 < 2; j2++)
          acc[i][j2] = mfma_bf16(af[i], bfv[j2], acc[i][j2]);
    }
  }

  const int rb = (lane >> 4) * 4;
#pragma unroll
  for (int i = 0; i < 4; i++)
#pragma unroll
    for (int j2 = 0; j2 < 2; j2++) {
      const int n = n0 + wn * 32 + j2 * 16 + fr;
#pragma unroll
      for (int r = 0; r < 4; r++) {
        const int m = m0 + wm * 64 + i * 16 + rb + r;
        const long idx = (long)m * N + n;
        C[idx] = acc[i][j2][r] + resid[idx];
      }
    }
}

// ---------------------------------------------------------------------------
// w3 GEMM, split-K x2: 768 blocks, each K-half of 1536 (24 steps).
// ---------------------------------------------------------------------------
__global__ __launch_bounds__(256)
void gemm_w3sk(const bf16* __restrict__ A, const bf16* __restrict__ W,
               float* __restrict__ p0, float* __restrict__ p1) {
  __shared__ __align__(16) bf16 As[128 * LDP];
  __shared__ __align__(16) bf16 Ws[64 * LDP];

  const int L  = blockIdx.x;
  const int j  = L >> 3;                  // 0..95
  const int mb = (L & 7) * 4 + (j / 24);
  const int inner = j % 24;
  const int s  = inner / 12;
  const int nb = inner % 12;
  const int m0 = mb * 128, n0 = nb * 64;
  const int K = FF_;
  const int kbase = s * 1536;
  float* C = s ? p1 : p0;

  const int tid = threadIdx.x;
  const int lane = tid & 63;
  const int wm = tid >> 7;
  const int wn = (tid >> 6) & 1;
  const int fr = lane & 15;
  const int fk = (lane >> 4) * 8;

  floatx4 acc[4][2] = {};

  const int ar = tid >> 3;
  const int ac = (tid & 7) * 8;
  const bf16* Aptr = A + (long)(m0 + ar) * K + kbase + ac;
  const bf16* Wptr = W + (long)(n0 + ar) * K + kbase + ac;
  const long rstep = (long)32 * K;

  bf16x8 apf[4], wpf[2];
#pragma unroll
  for (int c = 0; c < 4; c++) apf[c] = *(const bf16x8*)(Aptr + c * rstep);
#pragma unroll
  for (int c = 0; c < 2; c++) wpf[c] = *(const bf16x8*)(Wptr + c * rstep);

  const int ns = 24;
  for (int ks = 0; ks < ns; ks++) {
    __syncthreads();
#pragma unroll
    for (int c = 0; c < 4; c++) *(bf16x8*)&As[(ar + c * 32) * LDP + ac] = apf[c];
#pragma unroll
    for (int c = 0; c < 2; c++) *(bf16x8*)&Ws[(ar + c * 32) * LDP + ac] = wpf[c];
    __syncthreads();
    const long koff = (long)((ks + 1 < ns) ? ks + 1 : ks) * 64;
#pragma unroll
    for (int c = 0; c < 4; c++) apf[c] = *(const bf16x8*)(Aptr + koff + c * rstep);
#pragma unroll
    for (int c = 0; c < 2; c++) wpf[c] = *(const bf16x8*)(Wptr + koff + c * rstep);
#pragma unroll
    for (int kc = 0; kc < 2; kc++) {
      bf16x8 af[4], bfv[2];
#pragma unroll
      for (int i = 0; i < 4; i++) af[i]  = *(const bf16x8*)&As[(wm * 64 + i * 16 + fr) * LDP + kc * 32 + fk];
#pragma unroll
      for (int j2 = 0; j2 < 2; j2++) bfv[j2] = *(const bf16x8*)&Ws[(wn * 32 + j2 * 16 + fr) * LDP + kc * 32 + fk];
#pragma unroll
      for (int i = 0; i < 4; i++)
#pragma unroll
        for (int j2 = 0; j2 < 2; j2++)
          acc[i][j2] = mfma_bf16(af[i], bfv[j2], acc[i][j2]);
    }
  }

  const int rb = (lane >> 4) * 4;
#pragma unroll
  for (int i = 0; i < 4; i++)
#pragma unroll
    for (int j2 = 0; j2 < 2; j2++) {
      const int n = n0 + wn * 32 + j2 * 16 + fr;
#pragma unroll
      for (int r = 0; r < 4; r++) {
        const int m = m0 + wm * 64 + i * 16 + rb + r;
        C[(long)m * D_ + n] = acc[i][j2][r];
      }
    }
}

// out = p0 + p1 + xm (fp32), 3.1M elems, 8/thread.
__global__ __launch_bounds__(256)
void comb3_k(const float* __restrict__ p0, const float* __restrict__ p1,
             const float* __restrict__ xm, float* __restrict__ out) {
  const long i = ((long)blockIdx.x * 256 + threadIdx.x) * 8;
#pragma unroll
  for (int c = 0; c < 2; c++) {
    const floatx4 a = *(const floatx4*)&p0[i + c * 4];
    const floatx4 b = *(const floatx4*)&p1[i + c * 4];
    const floatx4 d = *(const floatx4*)&xm[i + c * 4];
    floatx4 r;
#pragma unroll
    for (int e = 0; e < 4; e++) r[e] = a[e] + b[e] + d[e];
    *(floatx4*)&out[i + c * 4] = r;
  }
}

// ---------------------------------------------------------------------------
// Fused w1/w2 GEMM + silu-mul. 128x128 DUAL tile, 768 blocks.
// ---------------------------------------------------------------------------
__global__ __launch_bounds__(256, 2)
void gemm_w12(const bf16* __restrict__ A, const bf16* __restrict__ W1,
              const bf16* __restrict__ W2, bf16* __restrict__ G) {
  __shared__ __align__(16) bf16 As[128 * LDP];
  __shared__ __align__(16) bf16 W1s[128 * LDP];
  __shared__ __align__(16) bf16 W2s[128 * LDP];

  const int L  = blockIdx.x;
  const int j  = L >> 3;                  // 0..95
  const int mb = j / 3;                   // 0..31 (outer per XCD)
  const int nb = (L & 7) * 3 + (j % 3);   // 0..23
  const int m0 = mb * 128, n0 = nb * 128;
  const int K = D_;

  const int tid = threadIdx.x;
  const int lane = tid & 63;
  const int wm = tid >> 7;
  const int wn = (tid >> 6) & 1;
  const int fr = lane & 15;
  const int fk = (lane >> 4) * 8;

  floatx4 acc1[4][4] = {}, acc2[4][4] = {};

  const int ar = tid >> 3;
  const int ac = (tid & 7) * 8;
  const bf16* Aptr  = A  + (long)(m0 + ar) * K + ac;
  const bf16* W1ptr = W1 + (long)(n0 + ar) * K + ac;
  const bf16* W2ptr = W2 + (long)(n0 + ar) * K + ac;
  const long rstep = (long)32 * K;

  bf16x8 apf[4], w1pf[4], w2pf[4];
#pragma unroll
  for (int c = 0; c < 4; c++) { apf[c]  = *(const bf16x8*)(Aptr  + c * rstep);
                                w1pf[c] = *(const bf16x8*)(W1ptr + c * rstep);
                                w2pf[c] = *(const bf16x8*)(W2ptr + c * rstep); }

  const int ns = K >> 6;   // 12
  for (int ks = 0; ks < ns; ks++) {
    __syncthreads();
#pragma unroll
    for (int c = 0; c < 4; c++) { *(bf16x8*)&As[(ar + c * 32) * LDP + ac]  = apf[c];
                                  *(bf16x8*)&W1s[(ar + c * 32) * LDP + ac] = w1pf[c];
                                  *(bf16x8*)&W2s[(ar + c * 32) * LDP + ac] = w2pf[c]; }
    __syncthreads();
    const long koff = (long)((ks + 1 < ns) ? ks + 1 : ks) * 64;
#pragma unroll
    for (int c = 0; c < 4; c++) { apf[c]  = *(const bf16x8*)(Aptr  + koff + c * rstep);
                                  w1pf[c] = *(const bf16x8*)(W1ptr + koff + c * rstep);
                                  w2pf[c] = *(const bf16x8*)(W2ptr + koff + c * rstep); }
#pragma unroll
    for (int kc = 0; kc < 2; kc++) {
      bf16x8 af[4];
#pragma unroll
      for (int i = 0; i < 4; i++) af[i] = *(const bf16x8*)&As[(wm * 64 + i * 16 + fr) * LDP + kc * 32 + fk];
      {
        bf16x8 b1[4];
#pragma unroll
        for (int jj = 0; jj < 4; jj++) b1[jj] = *(const bf16x8*)&W1s[(wn * 64 + jj * 16 + fr) * LDP + kc * 32 + fk];
#pragma unroll
        for (int i = 0; i < 4; i++)
#pragma unroll
          for (int jj = 0; jj < 4; jj++)
            acc1[i][jj] = mfma_bf16(af[i], b1[jj], acc1[i][jj]);
      }
      {
        bf16x8 b2[4];
#pragma unroll
        for (int jj = 0; jj < 4; jj++) b2[jj] = *(const bf16x8*)&W2s[(wn * 64 + jj * 16 + fr) * LDP + kc * 32 + fk];
#pragma unroll
        for (int i = 0; i < 4; i++)
#pragma unroll
          for (int jj = 0; jj < 4; jj++)
            acc2[i][jj] = mfma_bf16(af[i], b2[jj], acc2[i][jj]);
      }
    }
  }

  const int rb = (lane >> 4) * 4;
#pragma unroll
  for (int i = 0; i < 4; i++)
#pragma unroll
    for (int jj = 0; jj < 4; jj++) {
      const int n = n0 + wn * 64 + jj * 16 + fr;
#pragma unroll
      for (int r = 0; r < 4; r++) {
        const int m = m0 + wm * 64 + i * 16 + rb + r;
        const float a1 = acc1[i][jj][r];
        const float a2 = acc2[i][jj][r];
        const float s = a1 / (1.f + exp2f(-a1 * LOG2E));
        G[(long)m * FF_ + n] = (bf16)(s * a2);
      }
    }
}

// ---------------------------------------------------------------------------
// Flash attention, split-K over KV. blockIdx = r*24 + bh (24%8==0 -> all 80
// chunks of a bh land on XCD bh%8; 3 bh x 512KB K/V fits 4MB L2).
// Register-prefetch of next round's K/V overlaps global latency with compute.
// ---------------------------------------------------------------------------
__global__ __launch_bounds__(256, 4)
void flash_attn(const bf16* __restrict__ q, const bf16* __restrict__ k,
                const bf16* __restrict__ vtg, float* __restrict__ po,
                float* __restrict__ pm, float* __restrict__ pl) {
  const int gid = blockIdx.x;
  const int bh = gid % 24;
  const int r  = gid / 24;
  int qt, c;
  if (r < 8)       { qt = r; c = 0; }
  else if (r < 24) { qt = 8 + ((r - 8) >> 1); c = (r - 8) & 1; }
  else if (r < 48) { const int u = r - 24; const int d = u / 3; qt = 16 + d; c = u - d * 3; }
  else             { const int u = r - 48; qt = 24 + (u >> 2); c = u & 3; }
  const int b  = bh / H_;
  const int h  = bh % H_;
  const int q0 = qt * 64;
  const int tbeg = c * 8;
  const int tend = (tbeg + 7 < qt) ? tbeg + 7 : qt;

  __shared__ __align__(16) bf16 Qs[64][72];
  __shared__ __align__(16) bf16 Ks[64][72];
  __shared__ __align__(16) bf16 Vt[64][72];
  __shared__ __align__(16) bf16 Ps[4][16][72];

  const int tid = threadIdx.x, lane = tid & 63, w = tid >> 6;
  const int fr = lane & 15, quad = lane >> 4, fk = quad * 8;
  const long base = ((long)b * T_) * D_ + h * HD_;
  const long vbase = (long)bh * HD_ * T_;

  const int srow = tid >> 2, scol = (tid & 3) * 16;
  {
    const long g = base + (long)(q0 + srow) * D_ + scol;
    *(bf16x8*)&Qs[srow][scol]     = *(const bf16x8*)&q[g];
    *(bf16x8*)&Qs[srow][scol + 8] = *(const bf16x8*)&q[g + 8];
  }

  // prefetch round tbeg
  const bf16* kgp = k + base + (long)srow * D_ + scol;
  const bf16* vgp = vtg + vbase + (long)srow * T_ + scol;
  bf16x8 kpf0 = *(const bf16x8*)(kgp + (long)tbeg * 64 * D_);
  bf16x8 kpf1 = *(const bf16x8*)(kgp + (long)tbeg * 64 * D_ + 8);
  bf16x8 vpf0 = *(const bf16x8*)(vgp + tbeg * 64);
  bf16x8 vpf1 = *(const bf16x8*)(vgp + tbeg * 64 + 8);

  float m_st = -1e30f, l_st = 0.f;
  floatx4 o[4] = {};
  const float SC = 0.125f * LOG2E;

  for (int t = tbeg; t <= tend; t++) {
    __syncthreads();
    *(bf16x8*)&Ks[srow][scol]     = kpf0;
    *(bf16x8*)&Ks[srow][scol + 8] = kpf1;
    *(bf16x8*)&Vt[srow][scol]     = vpf0;
    *(bf16x8*)&Vt[srow][scol + 8] = vpf1;
    __syncthreads();
    // issue next round's loads (clamped on last iter)
    const int tn = (t + 1 <= tend) ? t + 1 : t;
    kpf0 = *(const bf16x8*)(kgp + (long)tn * 64 * D_);
    kpf1 = *(const bf16x8*)(kgp + (long)tn * 64 * D_ + 8);
    vpf0 = *(const bf16x8*)(vgp + tn * 64);
    vpf1 = *(const bf16x8*)(vgp + tn * 64 + 8);

    floatx4 s[4] = {};
#pragma unroll
    for (int kd = 0; kd < 2; kd++) {
      const bf16x8 bq = *(const bf16x8*)&Qs[w * 16 + fr][kd * 32 + fk];
#pragma unroll
      for (int kt = 0; kt < 4; kt++) {
        const bf16x8 ak = *(const bf16x8*)&Ks[kt * 16 + fr][kd * 32 + fk];
        s[kt] = mfma_bf16(ak, bq, s[kt]);
      }
    }

    if (t == qt) {
      const int qloc = w * 16 + fr;
#pragma unroll
      for (int kt = 0; kt < 4; kt++)
#pragma unroll
        for (int r2 = 0; r2 < 4; r2++) {
          const int kvloc = kt * 16 + quad * 4 + r2;
          s[kt][r2] = (kvloc > qloc) ? -1e30f : s[kt][r2] * SC;
        }
    } else {
#pragma unroll
      for (int kt = 0; kt < 4; kt++)
#pragma unroll
        for (int r2 = 0; r2 < 4; r2++) s[kt][r2] *= SC;
    }

    float mx = -1e30f;
#pragma unroll
    for (int kt = 0; kt < 4; kt++)
#pragma unroll
      for (int r2 = 0; r2 < 4; r2++) mx = fmaxf(mx, s[kt][r2]);
    mx = fmaxf(mx, __shfl_xor(mx, 16));
    mx = fmaxf(mx, __shfl_xor(mx, 32));
    const float mnew  = fmaxf(m_st, mx);
    const float alpha = exp2f(m_st - mnew);
    m_st = mnew;
    float rs = 0.f;
#pragma unroll
    for (int kt = 0; kt < 4; kt++)
#pragma unroll
      for (int r2 = 0; r2 < 4; r2++) {
        const float pv = exp2f(s[kt][r2] - mnew);
        s[kt][r2] = pv;
        rs += pv;
      }
    rs += __shfl_xor(rs, 16);
    rs += __shfl_xor(rs, 32);
    l_st = l_st * alpha + rs;
#pragma unroll
    for (int ht = 0; ht < 4; ht++) o[ht] *= alpha;

#pragma unroll
    for (int kt = 0; kt < 4; kt++) {
      bf16x4 pk;
#pragma unroll
      for (int r2 = 0; r2 < 4; r2++) pk[r2] = (bf16)s[kt][r2];
      *(bf16x4*)&Ps[w][fr][kt * 16 + quad * 4] = pk;
    }

#pragma unroll
    for (int kq = 0; kq < 2; kq++) {
      const bf16x8 bp = *(const bf16x8*)&Ps[w][fr][kq * 32 + fk];
#pragma unroll
      for (int ht = 0; ht < 4; ht++) {
        const bf16x8 av = *(const bf16x8*)&Vt[ht * 16 + fr][kq * 32 + fk];
        o[ht] = mfma_bf16(av, bp, o[ht]);
      }
    }
  }

  const int qq = w * 16 + fr;
  const long pg = (long)gid * 4096 + qq * 64;
#pragma unroll
  for (int ht = 0; ht < 4; ht++)
    *(floatx4*)&po[pg + ht * 16 + quad * 4] = o[ht];
  if (quad == 0) { pm[gid * 64 + qq] = m_st; pl[gid * 64 + qq] = l_st; }
}

// ---------------------------------------------------------------------------
// Combine flash split-K partials: block = (bh, qt), 768 blocks.
// Partial gid for chunk c of (bh,qt) is (bse+c)*24 + bh.
// ---------------------------------------------------------------------------
__global__ __launch_bounds__(256)
void flash_comb(const float* __restrict__ po, const float* __restrict__ pm,
                const float* __restrict__ pl, bf16* __restrict__ y) {
  const int bh = blockIdx.x >> 5;
  const int qt = blockIdx.x & 31;
  const int b = bh / H_, h = bh % H_;
  const int nc = (qt >> 3) + 1;
  int bse;
  if      (qt <  8) bse = qt;
  else if (qt < 16) bse = 8  + 2 * (qt - 8);
  else if (qt < 24) bse = 24 + 3 * (qt - 16);
  else              bse = 48 + 4 * (qt - 24);

  const int t = threadIdx.x;
  const int qq = t >> 2, hg = (t & 3) * 16;

  float M = -1e30f;
  for (int c2 = 0; c2 < nc; c2++) M = fmaxf(M, pm[((bse + c2) * 24 + bh) * 64 + qq]);
  float l = 0.f;
  floatx4 o[4] = {};
  for (int c2 = 0; c2 < nc; c2++) {
    const int g = (bse + c2) * 24 + bh;
    const float wgt = exp2f(pm[g * 64 + qq] - M);
    l += wgt * pl[g * 64 + qq];
    const long pg = (long)g * 4096 + qq * 64 + hg;
#pragma unroll
    for (int j = 0; j < 4; j++) {
      const floatx4 t4 = *(const floatx4*)&po[pg + j * 4];
#pragma unroll
      for (int e = 0; e < 4; e++) o[j][e] += wgt * t4[e];
    }
  }
  const float inv = 1.f / l;
  bf16x8 r0, r1;
#pragma unroll
  for (int e = 0; e < 4; e++) {
    r0[e]     = (bf16)(o[0][e] * inv);
    r0[4 + e] = (bf16)(o[1][e] * inv);
    r1[e]     = (bf16)(o[2][e] * inv);
    r1[4 + e] = (bf16)(o[3][e] * inv);
  }
  const long yoff = ((long)b * T_ + qt * 64 + qq) * D_ + h * HD_ + hg;
  *(bf16x8*)&y[yoff]     = r0;
  *(bf16x8*)&y[yoff + 8] = r1;
}

// ---------------------------------------------------------------------------
extern "C" void kernel_launch(void* const* d_in, const int* in_sizes, int n_in,
                              void* d_out, int out_size, void* d_ws, size_t ws_size,
                              hipStream_t stream) {
  const float* x    = (const float*)d_in[0];
  const float* wq   = (const float*)d_in[1];
  const float* wk   = (const float*)d_in[2];
  const float* wv   = (const float*)d_in[3];
  const float* wo   = (const float*)d_in[4];
  const float* w1   = (const float*)d_in[5];
  const float* w2   = (const float*)d_in[6];
  const float* w3   = (const float*)d_in[7];
  const float* anw  = (const float*)d_in[8];
  const float* fnw  = (const float*)d_in[9];
  const float* cosb = (const float*)d_in[10];
  const float* sinb = (const float*)d_in[11];

  char* ws = (char*)d_ws;
  // Layout (bytes), total 88,080,384. Aliasing by lifetime:
  //   po/pm/pl (flash->comb) overlay xm+g region (written later).
  //   w3 partials: p30 over qb+kb (dead after flash), p31 over yb+hn.
  bf16*  wb  = (bf16*)(ws + 0);                // 18,874,368
  bf16*  wqb = wb;
  bf16*  wkb = wb +  589824;
  bf16*  wvb = wb + 1179648;
  bf16*  wob = wb + 1769472;
  bf16*  w1b = wb + 2359296;
  bf16*  w2b = wb + 4718592;
  bf16*  w3b = wb + 7077888;
  bf16*  qb  = (bf16*)(ws + 18874368);
  bf16*  kb  = (bf16*)(ws + 25165824);
  bf16*  vt  = (bf16*)(ws + 31457280);
  bf16*  yb  = (bf16*)(ws + 37748736);
  bf16*  hn  = (bf16*)(ws + 44040192);
  float* xm  = (float*)(ws + 50331648);        // 12,582,912
  bf16*  g   = (bf16*)(ws + 62914560);         // 25,165,824
  float* po  = (float*)(ws + 50331648);        // 31,457,280 (pre-xm/g lifetime)
  float* pm  = (float*)(ws + 81788928);
  float* pl  = (float*)(ws + 82280448);
  float* p30 = (float*)(ws + 18874368);        // over qb+kb
  float* p31 = (float*)(ws + 37748736);        // over yb+hn

  prep_k<<<8704, 256, 0, stream>>>(wq, wk, wv, wo, w1, w2, w3, wb, x, anw, hn);
  gemm_qkv<<<dim3(18, 32), 256, 0, stream>>>(hn, wqb, wkb, wvb, qb, kb, vt, cosb, sinb);
  flash_attn<<<1920, 256, 0, stream>>>(qb, kb, vt, po, pm, pl);
  flash_comb<<<768, 256, 0, stream>>>(po, pm, pl, yb);
  gemm_n64<<<384, 256, 0, stream>>>(yb, wob, xm, x, 768, 768);
  rmsnorm_k<<<4096, 256, 0, stream>>>(xm, fnw, hn);
  gemm_w12<<<768, 256, 0, stream>>>(hn, w1b, w2b, g);
  gemm_w3sk<<<768, 256, 0, stream>>>(g, w3b, p30, p31);
  comb3_k<<<1536, 256, 0, stream>>>(p30, p31, xm, (float*)d_out);
}